// Round 9
// baseline (3989.378 us; speedup 1.0000x reference)
//
#include <hip/hip_runtime.h>
#include <hip/hip_bf16.h>

#define EPSF 1e-8f

// ---- workspace layout (floats) ----
#define OFF_WIT 0               // wiT4 [96 k4][1024 r] float4 = wi[r][4k4..+3]
#define N_WIT   393216
#define OFF_WHT 393216          // whT4 [64 k4][1024 r] float4
#define N_WHT   262144
#define OFF_PKT 655360          // pkT4 [64 k4][768 c] float4, c = m*256+o, m in {wk,wwk,wv}
#define N_PKT   196608
#define OFF_F1T 851968          // f1T4 [128 k4][256 o] float4
#define N_F1T   131072
#define OFF_F2T 983040          // f2T4 [64 k4][128 o] float4
#define N_F2T   32768
#define OFF_Z   1015808         // z [5120][128]
#define N_Z     655360
#define WS_FLOATS 1671168       // 6,684,672 bytes

// ---------- pack: transpose weights into ws (once per launch) ----------
__global__ __launch_bounds__(256) void pack_kernel(
    const float* __restrict__ wi, const float* __restrict__ wh,
    const float* __restrict__ wk, const float* __restrict__ wwk,
    const float* __restrict__ wv,
    const float* __restrict__ f1w, const float* __restrict__ f2w,
    float* __restrict__ ws) {
  int id = blockIdx.x * 256 + threadIdx.x;
  if (id < N_WIT) {  // ws[(k4*1024+r)*4+j] = wi[r*384 + k4*4 + j]
    int j = id & 3, r = (id >> 2) & 1023, k4 = id >> 12;
    ws[OFF_WIT + id] = wi[r * 384 + k4 * 4 + j];
    return;
  }
  id -= N_WIT;
  if (id < N_WHT) {  // ws[(k4*1024+r)*4+j] = wh[r*256 + k4*4 + j]
    int j = id & 3, r = (id >> 2) & 1023, k4 = id >> 12;
    ws[OFF_WHT + id] = wh[r * 256 + k4 * 4 + j];
    return;
  }
  id -= N_WHT;
  if (id < N_PKT) {  // ws[(k4*768+c)*4+j] = {wk,wwk,wv}[m][o*256 + k4*4 + j]
    int j = id & 3;
    int q = id >> 2;
    int c = q % 768, k4 = q / 768;
    int m = c >> 8, o = c & 255;
    int col = o * 256 + k4 * 4 + j;
    float v = (m == 0) ? wk[col] : (m == 1) ? wwk[col] : wv[col];
    ws[OFF_PKT + id] = v;
    return;
  }
  id -= N_PKT;
  if (id < N_F1T) {  // ws[(k4*256+o)*4+m] = f1w[o*512+4k4+m]
    int m = id & 3, o = (id >> 2) & 255, k4 = id >> 10;
    ws[OFF_F1T + id] = f1w[o * 512 + k4 * 4 + m];
    return;
  }
  id -= N_F1T;
  if (id < N_F2T) {  // ws[(k4*128+o)*4+m] = f2w[o*256+4k4+m]
    int m = id & 3, o = (id >> 2) & 127, k4 = id >> 9;
    ws[OFF_F2T + id] = f2w[o * 256 + k4 * 4 + m];
  }
}

// ---------- encoder: one block per frame; register patches + uniform weights ----------
__global__ __launch_bounds__(256) void enc_kernel(
    const float* __restrict__ x,
    const float* __restrict__ w1, const float* __restrict__ b1,
    const float* __restrict__ w2, const float* __restrict__ b2,
    const float* __restrict__ w3, const float* __restrict__ b3,
    const float* __restrict__ f1b, const float* __restrict__ f2b,
    float* __restrict__ ws) {
  __shared__ __align__(16) float xs[1024];        // 32x32
  __shared__ __align__(16) float c1s[512 * 19];   // 32ch x 16 rows, pad 19
  __shared__ __align__(16) float c2s[256 * 9];    // 32ch x 8 rows, pad 9
  __shared__ __align__(16) float c3s[512];        // 32 x 4 x 4 (NCHW flatten)
  __shared__ __align__(16) float h1s[256];

  const float4* __restrict__ f1T4 = (const float4*)(ws + OFF_F1T);
  const float4* __restrict__ f2T4 = (const float4*)(ws + OFF_F2T);
  float* __restrict__ z = ws + OFF_Z;

  const int f = blockIdx.x;  // = b*20 + t
  const int tid = threadIdx.x;

  for (int i = tid; i < 1024; i += 256) xs[i] = x[f * 1024 + i];
  __syncthreads();

  // conv1: thread = pixel (16x16); patch in regs; 32 ocs with uniform weights
  {
    int oy = tid >> 4, ox = tid & 15;
    float patch[16];
    #pragma unroll
    for (int ky = 0; ky < 4; ++ky) {
      int iy = oy * 2 - 1 + ky;
      #pragma unroll
      for (int kx = 0; kx < 4; ++kx) {
        int ix = ox * 2 - 1 + kx;
        patch[ky * 4 + kx] =
            ((unsigned)iy <= 31u && (unsigned)ix <= 31u) ? xs[iy * 32 + ix] : 0.f;
      }
    }
    for (int oc = 0; oc < 32; ++oc) {
      float acc = b1[oc];
      #pragma unroll
      for (int k = 0; k < 16; ++k) acc = fmaf(patch[k], w1[oc * 16 + k], acc);
      c1s[(oc * 16 + oy) * 19 + ox] = fmaxf(acc, 0.f);
    }
  }
  __syncthreads();

  // conv2: wave og handles ocs og*8..+7; lane = pixel of 8x8; patch regs per ic
  {
    int pix = tid & 63;
    int og = __builtin_amdgcn_readfirstlane(tid >> 6);
    int oy = pix >> 3, ox = pix & 7;
    float acc[8];
    #pragma unroll
    for (int j = 0; j < 8; ++j) acc[j] = b2[og * 8 + j];
    for (int ic = 0; ic < 32; ++ic) {
      float patch[16];
      #pragma unroll
      for (int ky = 0; ky < 4; ++ky) {
        int iy = oy * 2 - 1 + ky;
        #pragma unroll
        for (int kx = 0; kx < 4; ++kx) {
          int ix = ox * 2 - 1 + kx;
          patch[ky * 4 + kx] = ((unsigned)iy <= 15u && (unsigned)ix <= 15u)
                                   ? c1s[(ic * 16 + iy) * 19 + ix] : 0.f;
        }
      }
      #pragma unroll
      for (int j = 0; j < 8; ++j) {
        const float* wr = w2 + ((og * 8 + j) * 32 + ic) * 16;  // wave-uniform
        #pragma unroll
        for (int k = 0; k < 16; ++k) acc[j] = fmaf(patch[k], wr[k], acc[j]);
      }
    }
    #pragma unroll
    for (int j = 0; j < 8; ++j)
      c2s[((og * 8 + j) * 8 + oy) * 9 + ox] = fmaxf(acc[j], 0.f);
  }
  __syncthreads();

  // conv3: thread = (pixel of 4x4, grp of 2 ocs); patch regs per ic
  {
    int pix = tid & 15, grp = tid >> 4;
    int oy = pix >> 2, ox = pix & 3;
    float a0 = b3[grp * 2], a1 = b3[grp * 2 + 1];
    for (int ic = 0; ic < 32; ++ic) {
      float patch[16];
      #pragma unroll
      for (int ky = 0; ky < 4; ++ky) {
        int iy = oy * 2 - 1 + ky;
        #pragma unroll
        for (int kx = 0; kx < 4; ++kx) {
          int ix = ox * 2 - 1 + kx;
          patch[ky * 4 + kx] = ((unsigned)iy <= 7u && (unsigned)ix <= 7u)
                                   ? c2s[(ic * 8 + iy) * 9 + ix] : 0.f;
        }
      }
      const float4* wa = (const float4*)(w3 + ((grp * 2 + 0) * 32 + ic) * 16);
      const float4* wb = (const float4*)(w3 + ((grp * 2 + 1) * 32 + ic) * 16);
      #pragma unroll
      for (int q = 0; q < 4; ++q) {
        float4 qa = wa[q], qb = wb[q];
        a0 = fmaf(patch[q * 4 + 0], qa.x, a0);
        a0 = fmaf(patch[q * 4 + 1], qa.y, a0);
        a0 = fmaf(patch[q * 4 + 2], qa.z, a0);
        a0 = fmaf(patch[q * 4 + 3], qa.w, a0);
        a1 = fmaf(patch[q * 4 + 0], qb.x, a1);
        a1 = fmaf(patch[q * 4 + 1], qb.y, a1);
        a1 = fmaf(patch[q * 4 + 2], qb.z, a1);
        a1 = fmaf(patch[q * 4 + 3], qb.w, a1);
      }
    }
    c3s[(grp * 2 + 0) * 16 + pix] = fmaxf(a0, 0.f);
    c3s[(grp * 2 + 1) * 16 + pix] = fmaxf(a1, 0.f);
  }
  __syncthreads();

  // fc1: 512 -> 256, relu; coalesced float4 weights
  {
    float acc = f1b[tid];
    #pragma unroll 8
    for (int k4 = 0; k4 < 128; ++k4) {
      float4 cv = ((const float4*)c3s)[k4];
      float4 w = f1T4[k4 * 256 + tid];
      acc = fmaf(w.x, cv.x, acc);
      acc = fmaf(w.y, cv.y, acc);
      acc = fmaf(w.z, cv.z, acc);
      acc = fmaf(w.w, cv.w, acc);
    }
    h1s[tid] = fmaxf(acc, 0.f);
  }
  __syncthreads();

  // fc2: 256 -> 128, relu -> z
  if (tid < 128) {
    float acc = f2b[tid];
    #pragma unroll 8
    for (int k4 = 0; k4 < 64; ++k4) {
      float4 hv = ((const float4*)h1s)[k4];
      float4 w = f2T4[k4 * 128 + tid];
      acc = fmaf(w.x, hv.x, acc);
      acc = fmaf(w.y, hv.y, acc);
      acc = fmaf(w.z, hv.z, acc);
      acc = fmaf(w.w, hv.w, acc);
    }
    z[f * 128 + tid] = fmaxf(acc, 0.f);
  }
}

// ---------- context norm over time ----------
__global__ __launch_bounds__(256) void norm_kernel(
    float* __restrict__ ws,
    const float* __restrict__ gamma, const float* __restrict__ beta) {
  float* z = ws + OFF_Z;
  int g = blockIdx.x * 256 + threadIdx.x;  // B*D = 32768
  int b = g >> 7, d = g & 127;
  float vals[20];
  float mu = 0.f;
  #pragma unroll
  for (int t = 0; t < 20; ++t) {
    float v = z[(b * 20 + t) * 128 + d];
    vals[t] = v;
    mu += v;
  }
  mu *= (1.f / 20.f);
  float var = 0.f;
  #pragma unroll
  for (int t = 0; t < 20; ++t) {
    float dd = vals[t] - mu;
    var = fmaf(dd, dd, var);
  }
  var *= (1.f / 19.f);
  float inv = 1.f / sqrtf(var + EPSF);
  float ga = gamma[d], be = beta[d];
  #pragma unroll
  for (int t = 0; t < 20; ++t)
    z[(b * 20 + t) * 128 + d] = fmaf((vals[t] - mu) * inv, ga, be);
}

// ---------- scan: 1024 threads (4 waves/SIMD -> 128 VGPR budget), 2 batch/block ----------
__global__ __launch_bounds__(1024, 4) void scan_kernel(
    const float* __restrict__ ws,
    const float* __restrict__ lb, const float* __restrict__ wo,
    const float* __restrict__ wob, const float* __restrict__ mem_init,
    float* __restrict__ out) {
  __shared__ float Msh[2][20 * 257];
  __shared__ __align__(16) float gsh[2][1024];
  __shared__ __align__(16) float inp[2][384];   // [z(128) | r(256)]
  __shared__ __align__(16) float hsh[2][256];
  __shared__ float kqsh[2][2][256];             // [bl][head][k]
  __shared__ float vsh[2][256];
  __shared__ float sims[2][2][20];
  __shared__ float invq[2][2];
  __shared__ float wsel[2][2][4];
  __shared__ int isel[2][2][4];
  __shared__ float ysh[2][4];

  const int r = threadIdx.x;  // 0..1023
  const int b0 = blockIdx.x * 2;
  const float4* wiT4 = (const float4*)(ws + OFF_WIT);  // [96 k4][1024 r]
  const float4* whT4 = (const float4*)(ws + OFF_WHT);  // [64 k4][1024 r]
  const float4* pkT4 = (const float4*)(ws + OFF_PKT);  // [64 k4][768 c]
  const float* zz = ws + OFF_Z;

  #pragma unroll
  for (int bl = 0; bl < 2; ++bl)
    for (int idx = r; idx < 5120; idx += 1024)
      Msh[bl][(idx >> 8) * 257 + (idx & 255)] = mem_init[idx];
  if (r < 512) {
    int bl = r >> 8, u = r & 255;
    hsh[bl][u] = 0.f;
    inp[bl][128 + u] = 0.f;
  }
  float c_reg = 0.f;
  const float bias = lb[r];
  __syncthreads();

  for (int t = 0; t < 20; ++t) {
    if (r < 256) {
      int bl = r >> 7, d = r & 127;
      inp[bl][d] = zz[((b0 + bl) * 20 + t) * 128 + d];
    }
    __syncthreads();

    // gates: thread r = row r; 16-deep register staging of weight float4s
    float a0 = bias, a1 = bias;
    {
      const float4* ip0 = (const float4*)inp[0];
      const float4* ip1 = (const float4*)inp[1];
      float4 wreg[16];
      for (int ch = 0; ch < 6; ++ch) {  // wi: 96 k4 = 6 chunks of 16
        const float4* wp = wiT4 + (ch * 16) * 1024 + r;
        #pragma unroll
        for (int j = 0; j < 16; ++j) wreg[j] = wp[j * 1024];
        #pragma unroll
        for (int j = 0; j < 16; ++j) {
          int k4 = ch * 16 + j;
          float4 w = wreg[j];
          float4 z0 = ip0[k4], z1 = ip1[k4];
          a0 = fmaf(w.x, z0.x, a0); a1 = fmaf(w.x, z1.x, a1);
          a0 = fmaf(w.y, z0.y, a0); a1 = fmaf(w.y, z1.y, a1);
          a0 = fmaf(w.z, z0.z, a0); a1 = fmaf(w.z, z1.z, a1);
          a0 = fmaf(w.w, z0.w, a0); a1 = fmaf(w.w, z1.w, a1);
        }
      }
      const float4* hp0 = (const float4*)hsh[0];
      const float4* hp1 = (const float4*)hsh[1];
      for (int ch = 0; ch < 4; ++ch) {  // wh: 64 k4 = 4 chunks of 16
        const float4* wp = whT4 + (ch * 16) * 1024 + r;
        #pragma unroll
        for (int j = 0; j < 16; ++j) wreg[j] = wp[j * 1024];
        #pragma unroll
        for (int j = 0; j < 16; ++j) {
          int k4 = ch * 16 + j;
          float4 w = wreg[j];
          float4 h0 = hp0[k4], h1 = hp1[k4];
          a0 = fmaf(w.x, h0.x, a0); a1 = fmaf(w.x, h1.x, a1);
          a0 = fmaf(w.y, h0.y, a0); a1 = fmaf(w.y, h1.y, a1);
          a0 = fmaf(w.z, h0.z, a0); a1 = fmaf(w.z, h1.z, a1);
          a0 = fmaf(w.w, h0.w, a0); a1 = fmaf(w.w, h1.w, a1);
        }
      }
    }
    gsh[0][r] = a0;
    gsh[1][r] = a1;
    __syncthreads();

    // LSTM cell (torch order i,f,g,o); thread r<512 owns (bl, unit)
    if (r < 512) {
      int bl = r >> 8, u = r & 255;
      float ig = gsh[bl][u], fg = gsh[bl][256 + u];
      float gg = gsh[bl][512 + u], og = gsh[bl][768 + u];
      c_reg = (1.f / (1.f + expf(-fg))) * c_reg +
              (1.f / (1.f + expf(-ig))) * tanhf(gg);
      hsh[bl][u] = (1.f / (1.f + expf(-og))) * tanhf(c_reg);
    }
    __syncthreads();

    // head projections: thread r<768 owns one row of {wk,wwk,wv}, both bl
    if (r < 768) {
      int m = r >> 8, o = r & 255;
      float s0 = 0.f, s1 = 0.f;
      const float4* hp0 = (const float4*)hsh[0];
      const float4* hp1 = (const float4*)hsh[1];
      float4 wreg[16];
      for (int ch = 0; ch < 4; ++ch) {  // 64 k4 = 4 chunks of 16
        const float4* wp = pkT4 + (ch * 16) * 768 + r;
        #pragma unroll
        for (int j = 0; j < 16; ++j) wreg[j] = wp[j * 768];
        #pragma unroll
        for (int j = 0; j < 16; ++j) {
          int k4 = ch * 16 + j;
          float4 w = wreg[j];
          float4 h0 = hp0[k4], h1 = hp1[k4];
          s0 = fmaf(w.x, h0.x, s0); s1 = fmaf(w.x, h1.x, s1);
          s0 = fmaf(w.y, h0.y, s0); s1 = fmaf(w.y, h1.y, s1);
          s0 = fmaf(w.z, h0.z, s0); s1 = fmaf(w.z, h1.z, s1);
          s0 = fmaf(w.w, h0.w, s0); s1 = fmaf(w.w, h1.w, s1);
        }
      }
      if (m < 2) {
        kqsh[0][m][o] = s0;
        kqsh[1][m][o] = s1;
      } else {
        vsh[0][o] = tanhf(s0);
        vsh[1][o] = tanhf(s1);
      }
    }
    __syncthreads();

    // per-slot norms + sims (8 lanes/slot, shfl); query norms on r=320..323
    if (r < 320) {
      int bl = r >= 160;
      int q = bl ? r - 160 : r;
      int n = q >> 3, l = q & 7;
      const float* Mr = &Msh[bl][n * 257];
      float ss = 0.f, s1 = 0.f, s2 = 0.f;
      for (int i = 0; i < 32; ++i) {
        int k = l + 8 * i;
        float m = Mr[k];
        ss = fmaf(m, m, ss);
        s1 = fmaf(kqsh[bl][0][k], m, s1);
        s2 = fmaf(kqsh[bl][1][k], m, s2);
      }
      ss += __shfl_xor(ss, 1); s1 += __shfl_xor(s1, 1); s2 += __shfl_xor(s2, 1);
      ss += __shfl_xor(ss, 2); s1 += __shfl_xor(s1, 2); s2 += __shfl_xor(s2, 2);
      ss += __shfl_xor(ss, 4); s1 += __shfl_xor(s1, 4); s2 += __shfl_xor(s2, 4);
      if (l == 0) {
        float inv = 1.f / (sqrtf(ss) + EPSF);
        sims[bl][0][n] = s1 * inv;
        sims[bl][1][n] = s2 * inv;
      }
    } else if (r < 324) {
      int bl2 = (r - 320) >> 1, hd = r & 1;
      float qq = 0.f;
      for (int k = 0; k < 256; ++k) {
        float q = kqsh[bl2][hd][k];
        qq = fmaf(q, q, qq);
      }
      invq[bl2][hd] = 1.f / (sqrtf(qq) + EPSF);
    }
    __syncthreads();

    // top-4 (strict >, lowest index on tie) + softmax; 4 threads: (bl, head)
    if (r < 4) {
      int bl = r >> 1, hd = r & 1;
      const float* sm = sims[bl][hd];
      float inv = invq[bl][hd];
      unsigned mask = 0;
      float tv[4];
      int ti[4];
      for (int j = 0; j < 4; ++j) {
        float best = -3.4e38f;
        int bx = 0;
        for (int n = 0; n < 20; ++n)
          if (!((mask >> n) & 1u) && sm[n] > best) { best = sm[n]; bx = n; }
        mask |= 1u << bx;
        tv[j] = best * inv;
        ti[j] = bx;
      }
      float e0 = 1.f;
      float e1 = expf(tv[1] - tv[0]);
      float e2 = expf(tv[2] - tv[0]);
      float e3 = expf(tv[3] - tv[0]);
      float s = e0 + e1 + e2 + e3;
      wsel[bl][hd][0] = e0 / s; wsel[bl][hd][1] = e1 / s;
      wsel[bl][hd][2] = e2 / s; wsel[bl][hd][3] = e3 / s;
      isel[bl][hd][0] = ti[0]; isel[bl][hd][1] = ti[1];
      isel[bl][hd][2] = ti[2]; isel[bl][hd][3] = ti[3];
    }
    __syncthreads();

    // read gather (old M) then weighted scatter-add; (bl,u) column exclusive
    if (r < 512) {
      int bl = r >> 8, u = r & 255;
      float rvv = 0.f;
      #pragma unroll
      for (int j = 0; j < 4; ++j)
        rvv = fmaf(wsel[bl][0][j], Msh[bl][isel[bl][0][j] * 257 + u], rvv);
      float vv = vsh[bl][u];
      #pragma unroll
      for (int j = 0; j < 4; ++j)
        Msh[bl][isel[bl][1][j] * 257 + u] += wsel[bl][1][j] * vv;
      inp[bl][128 + u] = rvv;
    }
    __syncthreads();
  }

  // epilogue: y = [h, r] @ wo.T + wo_b; argmax (first max wins)
  if (r < 8) {
    int bl = r >> 2, o = r & 3;
    float acc = wob[o];
    const float* wr = wo + o * 512;
    for (int k = 0; k < 256; ++k) acc = fmaf(wr[k], hsh[bl][k], acc);
    for (int k = 0; k < 256; ++k) acc = fmaf(wr[256 + k], inp[bl][128 + k], acc);
    ysh[bl][o] = acc;
    out[(b0 + bl) * 4 + o] = acc;
  }
  __syncthreads();
  if (r < 2) {
    float best = ysh[r][0];
    int bx = 0;
    #pragma unroll
    for (int o = 1; o < 4; ++o)
      if (ysh[r][o] > best) { best = ysh[r][o]; bx = o; }
    out[1024 + b0 + r] = (float)bx;
  }
}

// ---------- fallback: proven round-4 single fused kernel (no workspace) ----------
__global__ __launch_bounds__(256) void fused_kernel(
    const float* __restrict__ x,
    const float* __restrict__ w1, const float* __restrict__ b1,
    const float* __restrict__ w2, const float* __restrict__ b2,
    const float* __restrict__ w3, const float* __restrict__ b3,
    const float* __restrict__ f1w, const float* __restrict__ f1b,
    const float* __restrict__ f2w, const float* __restrict__ f2b,
    const float* __restrict__ gamma, const float* __restrict__ beta,
    const float* __restrict__ wi, const float* __restrict__ wh,
    const float* __restrict__ lb, const float* __restrict__ wk,
    const float* __restrict__ wwk, const float* __restrict__ wv,
    const float* __restrict__ wo, const float* __restrict__ wob,
    const float* __restrict__ mem_init, float* __restrict__ out) {
  __shared__ float smem[15104];
  __shared__ float simr[20], simw[20], invq[2], wsel[2][4], ysh[4];
  __shared__ int isel[2][4];
  float* z_all = smem;
  float* pool = smem + 2560;
  float* xs = pool;
  float* c1s = pool + 1024;
  float* c2s = pool + 9216;
  float* c3s = pool + 11264;
  float* h1s = pool + 11776;
  float* w1s = pool + 12032;
  float* Msh = pool;
  float* inp = pool + 5140;
  float* hsh = pool + 5524;
  float* kqr = pool + 5780;
  float* kqw = pool + 6036;
  float* vsh = pool + 6292;
  const int tid = threadIdx.x;
  const int b = blockIdx.x;
  for (int i = tid; i < 512; i += 256) w1s[i] = w1[i];
  for (int f = 0; f < 20; ++f) {
    for (int i = tid; i < 1024; i += 256) xs[i] = x[(b * 20 + f) * 1024 + i];
    __syncthreads();
    for (int i = 0; i < 32; ++i) {
      int idx = i * 256 + tid;
      int oc = idx >> 8, pix = idx & 255, oy = pix >> 4, ox = pix & 15;
      float acc = b1[oc];
      for (int ky = 0; ky < 4; ++ky) {
        int iy = oy * 2 - 1 + ky;
        if ((unsigned)iy > 31u) continue;
        for (int kx = 0; kx < 4; ++kx) {
          int ix = ox * 2 - 1 + kx;
          if ((unsigned)ix > 31u) continue;
          acc = fmaf(xs[iy * 32 + ix], w1s[oc * 16 + ky * 4 + kx], acc);
        }
      }
      c1s[idx] = fmaxf(acc, 0.f);
    }
    __syncthreads();
    {
      int oc = tid >> 3, pg = tid & 7;
      float acc[8];
      float bb = b2[oc];
      for (int i = 0; i < 8; ++i) acc[i] = bb;
      for (int ic = 0; ic < 32; ++ic) {
        const float* in = &c1s[ic * 256];
        const float* wv_ = &w2[(oc * 32 + ic) * 16];
        for (int i = 0; i < 8; ++i) {
          int p = pg + 8 * i;
          int oy = p >> 3, ox = p & 7;
          for (int ky = 0; ky < 4; ++ky) {
            int iy = oy * 2 - 1 + ky;
            if ((unsigned)iy > 15u) continue;
            for (int kx = 0; kx < 4; ++kx) {
              int ix = ox * 2 - 1 + kx;
              if ((unsigned)ix > 15u) continue;
              acc[i] = fmaf(in[iy * 16 + ix], wv_[ky * 4 + kx], acc[i]);
            }
          }
        }
      }
      for (int i = 0; i < 8; ++i) c2s[oc * 64 + pg + 8 * i] = fmaxf(acc[i], 0.f);
    }
    __syncthreads();
    {
      int oc = tid >> 3, pg = tid & 7;
      float bb = b3[oc];
      float acc0 = bb, acc1 = bb;
      int p0 = pg, p1 = pg + 8;
      int oy0 = p0 >> 2, ox0 = p0 & 3, oy1 = p1 >> 2, ox1 = p1 & 3;
      for (int ic = 0; ic < 32; ++ic) {
        const float* in = &c2s[ic * 64];
        const float* wv_ = &w3[(oc * 32 + ic) * 16];
        for (int ky = 0; ky < 4; ++ky) {
          int iy0 = oy0 * 2 - 1 + ky, iy1 = oy1 * 2 - 1 + ky;
          for (int kx = 0; kx < 4; ++kx) {
            float w = wv_[ky * 4 + kx];
            int ix0 = ox0 * 2 - 1 + kx, ix1 = ox1 * 2 - 1 + kx;
            if ((unsigned)iy0 <= 7u && (unsigned)ix0 <= 7u)
              acc0 = fmaf(in[iy0 * 8 + ix0], w, acc0);
            if ((unsigned)iy1 <= 7u && (unsigned)ix1 <= 7u)
              acc1 = fmaf(in[iy1 * 8 + ix1], w, acc1);
          }
        }
      }
      c3s[oc * 16 + p0] = fmaxf(acc0, 0.f);
      c3s[oc * 16 + p1] = fmaxf(acc1, 0.f);
    }
    __syncthreads();
    {
      float acc = f1b[tid];
      const float* wr = f1w + tid * 512;
      for (int k = 0; k < 512; ++k) acc = fmaf(wr[k], c3s[k], acc);
      h1s[tid] = fmaxf(acc, 0.f);
    }
    __syncthreads();
    if (tid < 128) {
      float acc = f2b[tid];
      const float* wr = f2w + tid * 256;
      for (int k = 0; k < 256; ++k) acc = fmaf(wr[k], h1s[k], acc);
      z_all[f * 128 + tid] = fmaxf(acc, 0.f);
    }
    __syncthreads();
  }
  if (tid < 128) {
    float mu = 0.f;
    for (int t = 0; t < 20; ++t) mu += z_all[t * 128 + tid];
    mu *= (1.f / 20.f);
    float var = 0.f;
    for (int t = 0; t < 20; ++t) {
      float dd = z_all[t * 128 + tid] - mu;
      var = fmaf(dd, dd, var);
    }
    var *= (1.f / 19.f);
    float inv = 1.f / sqrtf(var + EPSF);
    float ga = gamma[tid], be = beta[tid];
    for (int t = 0; t < 20; ++t)
      z_all[t * 128 + tid] = fmaf((z_all[t * 128 + tid] - mu) * inv, ga, be);
  }
  for (int idx = tid; idx < 20 * 256; idx += 256)
    Msh[(idx >> 8) * 257 + (idx & 255)] = mem_init[idx];
  hsh[tid] = 0.f;
  inp[128 + tid] = 0.f;
  float c_reg = 0.f;
  __syncthreads();
  const int u = tid;
  for (int t = 0; t < 20; ++t) {
    if (u < 128) inp[u] = z_all[t * 128 + u];
    __syncthreads();
    float a[4];
    for (int g = 0; g < 4; ++g) {
      int row = g * 256 + u;
      float acc = lb[row];
      const float* wr = wi + row * 384;
      for (int k = 0; k < 384; ++k) acc = fmaf(wr[k], inp[k], acc);
      const float* hr = wh + row * 256;
      for (int k = 0; k < 256; ++k) acc = fmaf(hr[k], hsh[k], acc);
      a[g] = acc;
    }
    __syncthreads();
    {
      float ig = 1.f / (1.f + expf(-a[0]));
      float fg = 1.f / (1.f + expf(-a[1]));
      float gg = tanhf(a[2]);
      float og = 1.f / (1.f + expf(-a[3]));
      c_reg = fg * c_reg + ig * gg;
      hsh[u] = og * tanhf(c_reg);
    }
    __syncthreads();
    {
      float sk = 0.f, sw = 0.f, sv = 0.f;
      const float* rk = wk + u * 256;
      const float* rw = wwk + u * 256;
      const float* rv = wv + u * 256;
      for (int k = 0; k < 256; ++k) {
        float hv = hsh[k];
        sk = fmaf(rk[k], hv, sk);
        sw = fmaf(rw[k], hv, sw);
        sv = fmaf(rv[k], hv, sv);
      }
      kqr[u] = sk;
      kqw[u] = sw;
      vsh[u] = tanhf(sv);
    }
    __syncthreads();
    if (u < 20) {
      const float* Mr = &Msh[u * 257];
      float ss = 0.f, s1 = 0.f, s2 = 0.f;
      for (int k = 0; k < 256; ++k) {
        float m = Mr[k];
        ss = fmaf(m, m, ss);
        s1 = fmaf(kqr[k], m, s1);
        s2 = fmaf(kqw[k], m, s2);
      }
      float inv = 1.f / (sqrtf(ss) + EPSF);
      simr[u] = s1 * inv;
      simw[u] = s2 * inv;
    } else if (u == 20 || u == 21) {
      const float* q = (u == 20) ? kqr : kqw;
      float qq = 0.f;
      for (int k = 0; k < 256; ++k) qq = fmaf(q[k], q[k], qq);
      invq[u - 20] = 1.f / (sqrtf(qq) + EPSF);
    }
    __syncthreads();
    if (u < 2) {
      const float* sims = (u == 0) ? simr : simw;
      float inv = invq[u];
      unsigned mask = 0;
      float tv[4];
      int ti[4];
      for (int j = 0; j < 4; ++j) {
        float best = -3.4e38f;
        int bx = 0;
        for (int n = 0; n < 20; ++n)
          if (!((mask >> n) & 1u) && sims[n] > best) { best = sims[n]; bx = n; }
        mask |= 1u << bx;
        tv[j] = best * inv;
        ti[j] = bx;
      }
      float e1 = expf(tv[1] - tv[0]);
      float e2 = expf(tv[2] - tv[0]);
      float e3 = expf(tv[3] - tv[0]);
      float s = 1.f + e1 + e2 + e3;
      wsel[u][0] = 1.f / s; wsel[u][1] = e1 / s; wsel[u][2] = e2 / s; wsel[u][3] = e3 / s;
      isel[u][0] = ti[0]; isel[u][1] = ti[1]; isel[u][2] = ti[2]; isel[u][3] = ti[3];
    }
    __syncthreads();
    {
      float rvv = 0.f;
      for (int j = 0; j < 4; ++j)
        rvv = fmaf(wsel[0][j], Msh[isel[0][j] * 257 + u], rvv);
      float vv = vsh[u];
      for (int j = 0; j < 4; ++j)
        Msh[isel[1][j] * 257 + u] += wsel[1][j] * vv;
      inp[128 + u] = rvv;
    }
    __syncthreads();
  }
  if (u < 4) {
    float acc = wob[u];
    const float* wr = wo + u * 512;
    for (int k = 0; k < 256; ++k) acc = fmaf(wr[k], hsh[k], acc);
    for (int k = 0; k < 256; ++k) acc = fmaf(wr[256 + k], inp[128 + k], acc);
    ysh[u] = acc;
    out[b * 4 + u] = acc;
  }
  __syncthreads();
  if (u == 0) {
    float best = ysh[0];
    int bx = 0;
    for (int o = 1; o < 4; ++o)
      if (ysh[o] > best) { best = ysh[o]; bx = o; }
    out[1024 + b] = (float)bx;
  }
}

// ---------- launch ----------
extern "C" void kernel_launch(void* const* d_in, const int* in_sizes, int n_in,
                              void* d_out, int out_size, void* d_ws, size_t ws_size,
                              hipStream_t stream) {
  const float* x    = (const float*)d_in[0];
  const float* c1w  = (const float*)d_in[1];
  const float* c1b  = (const float*)d_in[2];
  const float* c2w  = (const float*)d_in[3];
  const float* c2b  = (const float*)d_in[4];
  const float* c3w  = (const float*)d_in[5];
  const float* c3b  = (const float*)d_in[6];
  const float* f1w  = (const float*)d_in[7];
  const float* f1b  = (const float*)d_in[8];
  const float* f2w  = (const float*)d_in[9];
  const float* f2b  = (const float*)d_in[10];
  const float* gam  = (const float*)d_in[11];
  const float* bet  = (const float*)d_in[12];
  const float* wi   = (const float*)d_in[13];
  const float* wh   = (const float*)d_in[14];
  const float* lb   = (const float*)d_in[15];
  const float* wk   = (const float*)d_in[16];
  const float* wwk  = (const float*)d_in[17];
  const float* wv   = (const float*)d_in[18];
  const float* wo   = (const float*)d_in[19];
  const float* wob  = (const float*)d_in[20];
  const float* mem0 = (const float*)d_in[21];
  float* out = (float*)d_out;

  if (ws_size >= (size_t)WS_FLOATS * sizeof(float)) {
    float* ws = (float*)d_ws;
    pack_kernel<<<3968, 256, 0, stream>>>(wi, wh, wk, wwk, wv, f1w, f2w, ws);
    enc_kernel<<<5120, 256, 0, stream>>>(x, c1w, c1b, c2w, c2b, c3w, c3b,
                                         f1b, f2b, ws);
    norm_kernel<<<128, 256, 0, stream>>>(ws, gam, bet);
    scan_kernel<<<128, 1024, 0, stream>>>(ws, lb, wo, wob, mem0, out);
  } else {
    fused_kernel<<<256, 256, 0, stream>>>(x, c1w, c1b, c2w, c2b, c3w, c3b,
                                          f1w, f1b, f2w, f2b, gam, bet,
                                          wi, wh, lb, wk, wwk, wv, wo, wob,
                                          mem0, out);
  }
}

// Round 10
// 1311.812 us; speedup vs baseline: 3.0411x; 3.0411x over previous
//
#include <hip/hip_runtime.h>
#include <hip/hip_bf16.h>

#define EPSF 1e-8f

// ---- workspace layout (floats) ----
#define OFF_WIT 0               // wiT4 [96 k4][1024 r] float4 = wi[r][4k4..+3]
#define N_WIT   393216
#define OFF_WHT 393216          // whT4 [64 k4][1024 r] float4
#define N_WHT   262144
#define OFF_PKT 655360          // pkT4 [64 k4][768 c] float4, c = m*256+o, m in {wk,wwk,wv}
#define N_PKT   196608
#define OFF_F1T 851968          // f1T4 [128 k4][256 o] float4
#define N_F1T   131072
#define OFF_F2T 983040          // f2T4 [64 k4][128 o] float4
#define N_F2T   32768
#define OFF_Z   1015808         // z [5120][128]
#define N_Z     655360
#define WS_BASE 1671168         // 6,684,672 bytes (tier-2)
#define OFF_GZ  1671168         // gz [5120 f][1024 r] = lb + wi[:, :128] @ z[f]
#define N_GZ    5242880
#define WS_FULL 6914048         // 27,656,192 bytes (tier-1)

// ---------- pack: transpose weights into ws (once per launch) ----------
__global__ __launch_bounds__(256) void pack_kernel(
    const float* __restrict__ wi, const float* __restrict__ wh,
    const float* __restrict__ wk, const float* __restrict__ wwk,
    const float* __restrict__ wv,
    const float* __restrict__ f1w, const float* __restrict__ f2w,
    float* __restrict__ ws) {
  int id = blockIdx.x * 256 + threadIdx.x;
  if (id < N_WIT) {  // ws[(k4*1024+r)*4+j] = wi[r*384 + k4*4 + j]
    int j = id & 3, r = (id >> 2) & 1023, k4 = id >> 12;
    ws[OFF_WIT + id] = wi[r * 384 + k4 * 4 + j];
    return;
  }
  id -= N_WIT;
  if (id < N_WHT) {  // ws[(k4*1024+r)*4+j] = wh[r*256 + k4*4 + j]
    int j = id & 3, r = (id >> 2) & 1023, k4 = id >> 12;
    ws[OFF_WHT + id] = wh[r * 256 + k4 * 4 + j];
    return;
  }
  id -= N_WHT;
  if (id < N_PKT) {  // ws[(k4*768+c)*4+j] = {wk,wwk,wv}[m][o*256 + k4*4 + j]
    int j = id & 3;
    int q = id >> 2;
    int c = q % 768, k4 = q / 768;
    int m = c >> 8, o = c & 255;
    int col = o * 256 + k4 * 4 + j;
    float v = (m == 0) ? wk[col] : (m == 1) ? wwk[col] : wv[col];
    ws[OFF_PKT + id] = v;
    return;
  }
  id -= N_PKT;
  if (id < N_F1T) {  // ws[(k4*256+o)*4+m] = f1w[o*512+4k4+m]
    int m = id & 3, o = (id >> 2) & 255, k4 = id >> 10;
    ws[OFF_F1T + id] = f1w[o * 512 + k4 * 4 + m];
    return;
  }
  id -= N_F1T;
  if (id < N_F2T) {  // ws[(k4*128+o)*4+m] = f2w[o*256+4k4+m]
    int m = id & 3, o = (id >> 2) & 127, k4 = id >> 9;
    ws[OFF_F2T + id] = f2w[o * 256 + k4 * 4 + m];
  }
}

// ---------- encoder: one block per frame; register patches + uniform weights ----------
__global__ __launch_bounds__(256) void enc_kernel(
    const float* __restrict__ x,
    const float* __restrict__ w1, const float* __restrict__ b1,
    const float* __restrict__ w2, const float* __restrict__ b2,
    const float* __restrict__ w3, const float* __restrict__ b3,
    const float* __restrict__ f1b, const float* __restrict__ f2b,
    float* __restrict__ ws) {
  __shared__ __align__(16) float xs[1024];        // 32x32
  __shared__ __align__(16) float c1s[512 * 19];   // 32ch x 16 rows, pad 19
  __shared__ __align__(16) float c2s[256 * 9];    // 32ch x 8 rows, pad 9
  __shared__ __align__(16) float c3s[512];        // 32 x 4 x 4 (NCHW flatten)
  __shared__ __align__(16) float h1s[256];

  const float4* __restrict__ f1T4 = (const float4*)(ws + OFF_F1T);
  const float4* __restrict__ f2T4 = (const float4*)(ws + OFF_F2T);
  float* __restrict__ z = ws + OFF_Z;

  const int f = blockIdx.x;  // = b*20 + t
  const int tid = threadIdx.x;

  for (int i = tid; i < 1024; i += 256) xs[i] = x[f * 1024 + i];
  __syncthreads();

  // conv1: thread = pixel (16x16); patch in regs; 32 ocs with uniform weights
  {
    int oy = tid >> 4, ox = tid & 15;
    float patch[16];
    #pragma unroll
    for (int ky = 0; ky < 4; ++ky) {
      int iy = oy * 2 - 1 + ky;
      #pragma unroll
      for (int kx = 0; kx < 4; ++kx) {
        int ix = ox * 2 - 1 + kx;
        patch[ky * 4 + kx] =
            ((unsigned)iy <= 31u && (unsigned)ix <= 31u) ? xs[iy * 32 + ix] : 0.f;
      }
    }
    for (int oc = 0; oc < 32; ++oc) {
      float acc = b1[oc];
      #pragma unroll
      for (int k = 0; k < 16; ++k) acc = fmaf(patch[k], w1[oc * 16 + k], acc);
      c1s[(oc * 16 + oy) * 19 + ox] = fmaxf(acc, 0.f);
    }
  }
  __syncthreads();

  // conv2: wave og handles ocs og*8..+7; lane = pixel of 8x8; patch regs per ic
  {
    int pix = tid & 63;
    int og = __builtin_amdgcn_readfirstlane(tid >> 6);
    int oy = pix >> 3, ox = pix & 7;
    float acc[8];
    #pragma unroll
    for (int j = 0; j < 8; ++j) acc[j] = b2[og * 8 + j];
    for (int ic = 0; ic < 32; ++ic) {
      float patch[16];
      #pragma unroll
      for (int ky = 0; ky < 4; ++ky) {
        int iy = oy * 2 - 1 + ky;
        #pragma unroll
        for (int kx = 0; kx < 4; ++kx) {
          int ix = ox * 2 - 1 + kx;
          patch[ky * 4 + kx] = ((unsigned)iy <= 15u && (unsigned)ix <= 15u)
                                   ? c1s[(ic * 16 + iy) * 19 + ix] : 0.f;
        }
      }
      #pragma unroll
      for (int j = 0; j < 8; ++j) {
        const float* wr = w2 + ((og * 8 + j) * 32 + ic) * 16;  // wave-uniform
        #pragma unroll
        for (int k = 0; k < 16; ++k) acc[j] = fmaf(patch[k], wr[k], acc[j]);
      }
    }
    #pragma unroll
    for (int j = 0; j < 8; ++j)
      c2s[((og * 8 + j) * 8 + oy) * 9 + ox] = fmaxf(acc[j], 0.f);
  }
  __syncthreads();

  // conv3: thread = (pixel of 4x4, grp of 2 ocs); patch regs per ic
  {
    int pix = tid & 15, grp = tid >> 4;
    int oy = pix >> 2, ox = pix & 3;
    float a0 = b3[grp * 2], a1 = b3[grp * 2 + 1];
    for (int ic = 0; ic < 32; ++ic) {
      float patch[16];
      #pragma unroll
      for (int ky = 0; ky < 4; ++ky) {
        int iy = oy * 2 - 1 + ky;
        #pragma unroll
        for (int kx = 0; kx < 4; ++kx) {
          int ix = ox * 2 - 1 + kx;
          patch[ky * 4 + kx] = ((unsigned)iy <= 7u && (unsigned)ix <= 7u)
                                   ? c2s[(ic * 8 + iy) * 9 + ix] : 0.f;
        }
      }
      const float4* wa = (const float4*)(w3 + ((grp * 2 + 0) * 32 + ic) * 16);
      const float4* wb = (const float4*)(w3 + ((grp * 2 + 1) * 32 + ic) * 16);
      #pragma unroll
      for (int q = 0; q < 4; ++q) {
        float4 qa = wa[q], qb = wb[q];
        a0 = fmaf(patch[q * 4 + 0], qa.x, a0);
        a0 = fmaf(patch[q * 4 + 1], qa.y, a0);
        a0 = fmaf(patch[q * 4 + 2], qa.z, a0);
        a0 = fmaf(patch[q * 4 + 3], qa.w, a0);
        a1 = fmaf(patch[q * 4 + 0], qb.x, a1);
        a1 = fmaf(patch[q * 4 + 1], qb.y, a1);
        a1 = fmaf(patch[q * 4 + 2], qb.z, a1);
        a1 = fmaf(patch[q * 4 + 3], qb.w, a1);
      }
    }
    c3s[(grp * 2 + 0) * 16 + pix] = fmaxf(a0, 0.f);
    c3s[(grp * 2 + 1) * 16 + pix] = fmaxf(a1, 0.f);
  }
  __syncthreads();

  // fc1: 512 -> 256, relu; coalesced float4 weights
  {
    float acc = f1b[tid];
    #pragma unroll 8
    for (int k4 = 0; k4 < 128; ++k4) {
      float4 cv = ((const float4*)c3s)[k4];
      float4 w = f1T4[k4 * 256 + tid];
      acc = fmaf(w.x, cv.x, acc);
      acc = fmaf(w.y, cv.y, acc);
      acc = fmaf(w.z, cv.z, acc);
      acc = fmaf(w.w, cv.w, acc);
    }
    h1s[tid] = fmaxf(acc, 0.f);
  }
  __syncthreads();

  // fc2: 256 -> 128, relu -> z
  if (tid < 128) {
    float acc = f2b[tid];
    #pragma unroll 8
    for (int k4 = 0; k4 < 64; ++k4) {
      float4 hv = ((const float4*)h1s)[k4];
      float4 w = f2T4[k4 * 128 + tid];
      acc = fmaf(w.x, hv.x, acc);
      acc = fmaf(w.y, hv.y, acc);
      acc = fmaf(w.z, hv.z, acc);
      acc = fmaf(w.w, hv.w, acc);
    }
    z[f * 128 + tid] = fmaxf(acc, 0.f);
  }
}

// ---------- context norm over time ----------
__global__ __launch_bounds__(256) void norm_kernel(
    float* __restrict__ ws,
    const float* __restrict__ gamma, const float* __restrict__ beta) {
  float* z = ws + OFF_Z;
  int g = blockIdx.x * 256 + threadIdx.x;  // B*D = 32768
  int b = g >> 7, d = g & 127;
  float vals[20];
  float mu = 0.f;
  #pragma unroll
  for (int t = 0; t < 20; ++t) {
    float v = z[(b * 20 + t) * 128 + d];
    vals[t] = v;
    mu += v;
  }
  mu *= (1.f / 20.f);
  float var = 0.f;
  #pragma unroll
  for (int t = 0; t < 20; ++t) {
    float dd = vals[t] - mu;
    var = fmaf(dd, dd, var);
  }
  var *= (1.f / 19.f);
  float inv = 1.f / sqrtf(var + EPSF);
  float ga = gamma[d], be = beta[d];
  #pragma unroll
  for (int t = 0; t < 20; ++t)
    z[(b * 20 + t) * 128 + d] = fmaf((vals[t] - mu) * inv, ga, be);
}

// ---------- gz: gates_z[f][r] = lb[r] + wi[r, :128] @ z[f]  (recurrence-free) ----------
// Same accumulation order as the scan previously used (bias, then k ascending),
// so the final gate sums are bit-identical.
__global__ __launch_bounds__(512) void gz_kernel(
    const float* __restrict__ ws, const float* __restrict__ lb,
    float* __restrict__ gz) {
  __shared__ __align__(16) float zs[16][128];
  const float4* wiT4 = (const float4*)(ws + OFF_WIT);  // [96 k4][1024 r]
  const float* zz = ws + OFF_Z;
  const int tid = threadIdx.x;
  const int f0 = blockIdx.x * 16;

  for (int i = tid; i < 2048; i += 512) zs[i >> 7][i & 127] = zz[f0 * 128 + i];
  __syncthreads();

  float acc0[16], acc1[16];
  const float b0v = lb[tid], b1v = lb[tid + 512];
  #pragma unroll
  for (int f = 0; f < 16; ++f) { acc0[f] = b0v; acc1[f] = b1v; }

  for (int k4 = 0; k4 < 32; ++k4) {  // k < 128: the z part of wi
    float4 w0 = wiT4[k4 * 1024 + tid];
    float4 w1 = wiT4[k4 * 1024 + tid + 512];
    #pragma unroll
    for (int f = 0; f < 16; ++f) {
      float4 zv = *(const float4*)&zs[f][k4 * 4];  // uniform addr -> broadcast
      acc0[f] = fmaf(w0.x, zv.x, acc0[f]);
      acc0[f] = fmaf(w0.y, zv.y, acc0[f]);
      acc0[f] = fmaf(w0.z, zv.z, acc0[f]);
      acc0[f] = fmaf(w0.w, zv.w, acc0[f]);
      acc1[f] = fmaf(w1.x, zv.x, acc1[f]);
      acc1[f] = fmaf(w1.y, zv.y, acc1[f]);
      acc1[f] = fmaf(w1.z, zv.z, acc1[f]);
      acc1[f] = fmaf(w1.w, zv.w, acc1[f]);
    }
  }
  #pragma unroll
  for (int f = 0; f < 16; ++f) {
    gz[(f0 + f) * 1024 + tid] = acc0[f];
    gz[(f0 + f) * 1024 + 512 + tid] = acc1[f];
  }
}

// ---------- scan: 1024 threads, 2 batch/block; optional precomputed gz ----------
__global__ __launch_bounds__(1024, 2) void scan_kernel(
    const float* __restrict__ ws, const float* __restrict__ gz,
    const float* __restrict__ lb, const float* __restrict__ wo,
    const float* __restrict__ wob, const float* __restrict__ mem_init,
    float* __restrict__ out) {
  __shared__ float Msh[2][20 * 257];
  __shared__ __align__(16) float gsh[2][1024];
  __shared__ __align__(16) float inp[2][384];   // [z(128) | r(256)]
  __shared__ __align__(16) float hsh[2][256];
  __shared__ float kqsh[2][2][256];             // [bl][head][k]
  __shared__ float vsh[2][256];
  __shared__ float sims[2][2][20];
  __shared__ float invq[2][2];
  __shared__ float wsel[2][2][4];
  __shared__ int isel[2][2][4];
  __shared__ float ysh[2][4];

  const int r = threadIdx.x;  // 0..1023
  const int b0 = blockIdx.x * 2;
  const float4* wiT4 = (const float4*)(ws + OFF_WIT);  // [96 k4][1024 r]
  const float4* whT4 = (const float4*)(ws + OFF_WHT);  // [64 k4][1024 r]
  const float4* pkT4 = (const float4*)(ws + OFF_PKT);  // [64 k4][768 c]
  const float* zz = ws + OFF_Z;
  const int k4s = gz ? 32 : 0;  // with gz, wi's z-columns are prefolded

  #pragma unroll
  for (int bl = 0; bl < 2; ++bl)
    for (int idx = r; idx < 5120; idx += 1024)
      Msh[bl][(idx >> 8) * 257 + (idx & 255)] = mem_init[idx];
  if (r < 512) {
    int bl = r >> 8, u = r & 255;
    hsh[bl][u] = 0.f;
    inp[bl][128 + u] = 0.f;
  }
  float c_reg = 0.f;
  const float bias = lb[r];
  __syncthreads();

  for (int t = 0; t < 20; ++t) {
    if (!gz && r < 256) {
      int bl = r >> 7, d = r & 127;
      inp[bl][d] = zz[((b0 + bl) * 20 + t) * 128 + d];
    }
    __syncthreads();

    // gates: thread r = row r; both batch elements from one weight load
    float a0, a1;
    if (gz) {
      a0 = gz[(b0 * 20 + t) * 1024 + r];
      a1 = gz[((b0 + 1) * 20 + t) * 1024 + r];
    } else {
      a0 = bias;
      a1 = bias;
    }
    {
      const float4* ip0 = (const float4*)inp[0];
      const float4* ip1 = (const float4*)inp[1];
      #pragma unroll 8
      for (int k4 = k4s; k4 < 96; ++k4) {
        float4 w = wiT4[k4 * 1024 + r];
        float4 z0 = ip0[k4], z1 = ip1[k4];
        a0 = fmaf(w.x, z0.x, a0); a1 = fmaf(w.x, z1.x, a1);
        a0 = fmaf(w.y, z0.y, a0); a1 = fmaf(w.y, z1.y, a1);
        a0 = fmaf(w.z, z0.z, a0); a1 = fmaf(w.z, z1.z, a1);
        a0 = fmaf(w.w, z0.w, a0); a1 = fmaf(w.w, z1.w, a1);
      }
      const float4* hp0 = (const float4*)hsh[0];
      const float4* hp1 = (const float4*)hsh[1];
      #pragma unroll 8
      for (int k4 = 0; k4 < 64; ++k4) {
        float4 w = whT4[k4 * 1024 + r];
        float4 h0 = hp0[k4], h1 = hp1[k4];
        a0 = fmaf(w.x, h0.x, a0); a1 = fmaf(w.x, h1.x, a1);
        a0 = fmaf(w.y, h0.y, a0); a1 = fmaf(w.y, h1.y, a1);
        a0 = fmaf(w.z, h0.z, a0); a1 = fmaf(w.z, h1.z, a1);
        a0 = fmaf(w.w, h0.w, a0); a1 = fmaf(w.w, h1.w, a1);
      }
    }
    gsh[0][r] = a0;
    gsh[1][r] = a1;
    __syncthreads();

    // LSTM cell (torch order i,f,g,o); thread r<512 owns (bl, unit)
    if (r < 512) {
      int bl = r >> 8, u = r & 255;
      float ig = gsh[bl][u], fg = gsh[bl][256 + u];
      float gg = gsh[bl][512 + u], og = gsh[bl][768 + u];
      c_reg = (1.f / (1.f + expf(-fg))) * c_reg +
              (1.f / (1.f + expf(-ig))) * tanhf(gg);
      hsh[bl][u] = (1.f / (1.f + expf(-og))) * tanhf(c_reg);
    }
    __syncthreads();

    // head projections: thread r<768 owns one row of {wk,wwk,wv}, both bl
    if (r < 768) {
      int m = r >> 8, o = r & 255;
      float s0 = 0.f, s1 = 0.f;
      const float4* hp0 = (const float4*)hsh[0];
      const float4* hp1 = (const float4*)hsh[1];
      #pragma unroll 8
      for (int k4 = 0; k4 < 64; ++k4) {
        float4 w = pkT4[k4 * 768 + r];
        float4 h0 = hp0[k4], h1 = hp1[k4];
        s0 = fmaf(w.x, h0.x, s0); s1 = fmaf(w.x, h1.x, s1);
        s0 = fmaf(w.y, h0.y, s0); s1 = fmaf(w.y, h1.y, s1);
        s0 = fmaf(w.z, h0.z, s0); s1 = fmaf(w.z, h1.z, s1);
        s0 = fmaf(w.w, h0.w, s0); s1 = fmaf(w.w, h1.w, s1);
      }
      if (m < 2) {
        kqsh[0][m][o] = s0;
        kqsh[1][m][o] = s1;
      } else {
        vsh[0][o] = tanhf(s0);
        vsh[1][o] = tanhf(s1);
      }
    }
    __syncthreads();

    // per-slot norms + sims (8 lanes/slot, shfl); query norms on r=320..323
    if (r < 320) {
      int bl = r >= 160;
      int q = bl ? r - 160 : r;
      int n = q >> 3, l = q & 7;
      const float* Mr = &Msh[bl][n * 257];
      float ss = 0.f, s1 = 0.f, s2 = 0.f;
      for (int i = 0; i < 32; ++i) {
        int k = l + 8 * i;
        float m = Mr[k];
        ss = fmaf(m, m, ss);
        s1 = fmaf(kqsh[bl][0][k], m, s1);
        s2 = fmaf(kqsh[bl][1][k], m, s2);
      }
      ss += __shfl_xor(ss, 1); s1 += __shfl_xor(s1, 1); s2 += __shfl_xor(s2, 1);
      ss += __shfl_xor(ss, 2); s1 += __shfl_xor(s1, 2); s2 += __shfl_xor(s2, 2);
      ss += __shfl_xor(ss, 4); s1 += __shfl_xor(s1, 4); s2 += __shfl_xor(s2, 4);
      if (l == 0) {
        float inv = 1.f / (sqrtf(ss) + EPSF);
        sims[bl][0][n] = s1 * inv;
        sims[bl][1][n] = s2 * inv;
      }
    } else if (r < 324) {
      int bl2 = (r - 320) >> 1, hd = r & 1;
      float qq = 0.f;
      for (int k = 0; k < 256; ++k) {
        float q = kqsh[bl2][hd][k];
        qq = fmaf(q, q, qq);
      }
      invq[bl2][hd] = 1.f / (sqrtf(qq) + EPSF);
    }
    __syncthreads();

    // top-4 (strict >, lowest index on tie) + softmax; 4 threads: (bl, head)
    if (r < 4) {
      int bl = r >> 1, hd = r & 1;
      const float* sm = sims[bl][hd];
      float inv = invq[bl][hd];
      unsigned mask = 0;
      float tv[4];
      int ti[4];
      for (int j = 0; j < 4; ++j) {
        float best = -3.4e38f;
        int bx = 0;
        for (int n = 0; n < 20; ++n)
          if (!((mask >> n) & 1u) && sm[n] > best) { best = sm[n]; bx = n; }
        mask |= 1u << bx;
        tv[j] = best * inv;
        ti[j] = bx;
      }
      float e0 = 1.f;
      float e1 = expf(tv[1] - tv[0]);
      float e2 = expf(tv[2] - tv[0]);
      float e3 = expf(tv[3] - tv[0]);
      float s = e0 + e1 + e2 + e3;
      wsel[bl][hd][0] = e0 / s; wsel[bl][hd][1] = e1 / s;
      wsel[bl][hd][2] = e2 / s; wsel[bl][hd][3] = e3 / s;
      isel[bl][hd][0] = ti[0]; isel[bl][hd][1] = ti[1];
      isel[bl][hd][2] = ti[2]; isel[bl][hd][3] = ti[3];
    }
    __syncthreads();

    // read gather (old M) then weighted scatter-add; (bl,u) column exclusive
    if (r < 512) {
      int bl = r >> 8, u = r & 255;
      float rvv = 0.f;
      #pragma unroll
      for (int j = 0; j < 4; ++j)
        rvv = fmaf(wsel[bl][0][j], Msh[bl][isel[bl][0][j] * 257 + u], rvv);
      float vv = vsh[bl][u];
      #pragma unroll
      for (int j = 0; j < 4; ++j)
        Msh[bl][isel[bl][1][j] * 257 + u] += wsel[bl][1][j] * vv;
      inp[bl][128 + u] = rvv;
    }
    __syncthreads();
  }

  // epilogue: y = [h, r] @ wo.T + wo_b; argmax (first max wins)
  if (r < 8) {
    int bl = r >> 2, o = r & 3;
    float acc = wob[o];
    const float* wr = wo + o * 512;
    for (int k = 0; k < 256; ++k) acc = fmaf(wr[k], hsh[bl][k], acc);
    for (int k = 0; k < 256; ++k) acc = fmaf(wr[256 + k], inp[bl][128 + k], acc);
    ysh[bl][o] = acc;
    out[(b0 + bl) * 4 + o] = acc;
  }
  __syncthreads();
  if (r < 2) {
    float best = ysh[r][0];
    int bx = 0;
    #pragma unroll
    for (int o = 1; o < 4; ++o)
      if (ysh[r][o] > best) { best = ysh[r][o]; bx = o; }
    out[1024 + b0 + r] = (float)bx;
  }
}

// ---------- fallback: proven round-4 single fused kernel (no workspace) ----------
__global__ __launch_bounds__(256) void fused_kernel(
    const float* __restrict__ x,
    const float* __restrict__ w1, const float* __restrict__ b1,
    const float* __restrict__ w2, const float* __restrict__ b2,
    const float* __restrict__ w3, const float* __restrict__ b3,
    const float* __restrict__ f1w, const float* __restrict__ f1b,
    const float* __restrict__ f2w, const float* __restrict__ f2b,
    const float* __restrict__ gamma, const float* __restrict__ beta,
    const float* __restrict__ wi, const float* __restrict__ wh,
    const float* __restrict__ lb, const float* __restrict__ wk,
    const float* __restrict__ wwk, const float* __restrict__ wv,
    const float* __restrict__ wo, const float* __restrict__ wob,
    const float* __restrict__ mem_init, float* __restrict__ out) {
  __shared__ float smem[15104];
  __shared__ float simr[20], simw[20], invq[2], wsel[2][4], ysh[4];
  __shared__ int isel[2][4];
  float* z_all = smem;
  float* pool = smem + 2560;
  float* xs = pool;
  float* c1s = pool + 1024;
  float* c2s = pool + 9216;
  float* c3s = pool + 11264;
  float* h1s = pool + 11776;
  float* w1s = pool + 12032;
  float* Msh = pool;
  float* inp = pool + 5140;
  float* hsh = pool + 5524;
  float* kqr = pool + 5780;
  float* kqw = pool + 6036;
  float* vsh = pool + 6292;
  const int tid = threadIdx.x;
  const int b = blockIdx.x;
  for (int i = tid; i < 512; i += 256) w1s[i] = w1[i];
  for (int f = 0; f < 20; ++f) {
    for (int i = tid; i < 1024; i += 256) xs[i] = x[(b * 20 + f) * 1024 + i];
    __syncthreads();
    for (int i = 0; i < 32; ++i) {
      int idx = i * 256 + tid;
      int oc = idx >> 8, pix = idx & 255, oy = pix >> 4, ox = pix & 15;
      float acc = b1[oc];
      for (int ky = 0; ky < 4; ++ky) {
        int iy = oy * 2 - 1 + ky;
        if ((unsigned)iy > 31u) continue;
        for (int kx = 0; kx < 4; ++kx) {
          int ix = ox * 2 - 1 + kx;
          if ((unsigned)ix > 31u) continue;
          acc = fmaf(xs[iy * 32 + ix], w1s[oc * 16 + ky * 4 + kx], acc);
        }
      }
      c1s[idx] = fmaxf(acc, 0.f);
    }
    __syncthreads();
    {
      int oc = tid >> 3, pg = tid & 7;
      float acc[8];
      float bb = b2[oc];
      for (int i = 0; i < 8; ++i) acc[i] = bb;
      for (int ic = 0; ic < 32; ++ic) {
        const float* in = &c1s[ic * 256];
        const float* wv_ = &w2[(oc * 32 + ic) * 16];
        for (int i = 0; i < 8; ++i) {
          int p = pg + 8 * i;
          int oy = p >> 3, ox = p & 7;
          for (int ky = 0; ky < 4; ++ky) {
            int iy = oy * 2 - 1 + ky;
            if ((unsigned)iy > 15u) continue;
            for (int kx = 0; kx < 4; ++kx) {
              int ix = ox * 2 - 1 + kx;
              if ((unsigned)ix > 15u) continue;
              acc[i] = fmaf(in[iy * 16 + ix], wv_[ky * 4 + kx], acc[i]);
            }
          }
        }
      }
      for (int i = 0; i < 8; ++i) c2s[oc * 64 + pg + 8 * i] = fmaxf(acc[i], 0.f);
    }
    __syncthreads();
    {
      int oc = tid >> 3, pg = tid & 7;
      float bb = b3[oc];
      float acc0 = bb, acc1 = bb;
      int p0 = pg, p1 = pg + 8;
      int oy0 = p0 >> 2, ox0 = p0 & 3, oy1 = p1 >> 2, ox1 = p1 & 3;
      for (int ic = 0; ic < 32; ++ic) {
        const float* in = &c2s[ic * 64];
        const float* wv_ = &w3[(oc * 32 + ic) * 16];
        for (int ky = 0; ky < 4; ++ky) {
          int iy0 = oy0 * 2 - 1 + ky, iy1 = oy1 * 2 - 1 + ky;
          for (int kx = 0; kx < 4; ++kx) {
            float w = wv_[ky * 4 + kx];
            int ix0 = ox0 * 2 - 1 + kx, ix1 = ox1 * 2 - 1 + kx;
            if ((unsigned)iy0 <= 7u && (unsigned)ix0 <= 7u)
              acc0 = fmaf(in[iy0 * 8 + ix0], w, acc0);
            if ((unsigned)iy1 <= 7u && (unsigned)ix1 <= 7u)
              acc1 = fmaf(in[iy1 * 8 + ix1], w, acc1);
          }
        }
      }
      c3s[oc * 16 + p0] = fmaxf(acc0, 0.f);
      c3s[oc * 16 + p1] = fmaxf(acc1, 0.f);
    }
    __syncthreads();
    {
      float acc = f1b[tid];
      const float* wr = f1w + tid * 512;
      for (int k = 0; k < 512; ++k) acc = fmaf(wr[k], c3s[k], acc);
      h1s[tid] = fmaxf(acc, 0.f);
    }
    __syncthreads();
    if (tid < 128) {
      float acc = f2b[tid];
      const float* wr = f2w + tid * 256;
      for (int k = 0; k < 256; ++k) acc = fmaf(wr[k], h1s[k], acc);
      z_all[f * 128 + tid] = fmaxf(acc, 0.f);
    }
    __syncthreads();
  }
  if (tid < 128) {
    float mu = 0.f;
    for (int t = 0; t < 20; ++t) mu += z_all[t * 128 + tid];
    mu *= (1.f / 20.f);
    float var = 0.f;
    for (int t = 0; t < 20; ++t) {
      float dd = z_all[t * 128 + tid] - mu;
      var = fmaf(dd, dd, var);
    }
    var *= (1.f / 19.f);
    float inv = 1.f / sqrtf(var + EPSF);
    float ga = gamma[tid], be = beta[tid];
    for (int t = 0; t < 20; ++t)
      z_all[t * 128 + tid] = fmaf((z_all[t * 128 + tid] - mu) * inv, ga, be);
  }
  for (int idx = tid; idx < 20 * 256; idx += 256)
    Msh[(idx >> 8) * 257 + (idx & 255)] = mem_init[idx];
  hsh[tid] = 0.f;
  inp[128 + tid] = 0.f;
  float c_reg = 0.f;
  __syncthreads();
  const int u = tid;
  for (int t = 0; t < 20; ++t) {
    if (u < 128) inp[u] = z_all[t * 128 + u];
    __syncthreads();
    float a[4];
    for (int g = 0; g < 4; ++g) {
      int row = g * 256 + u;
      float acc = lb[row];
      const float* wr = wi + row * 384;
      for (int k = 0; k < 384; ++k) acc = fmaf(wr[k], inp[k], acc);
      const float* hr = wh + row * 256;
      for (int k = 0; k < 256; ++k) acc = fmaf(hr[k], hsh[k], acc);
      a[g] = acc;
    }
    __syncthreads();
    {
      float ig = 1.f / (1.f + expf(-a[0]));
      float fg = 1.f / (1.f + expf(-a[1]));
      float gg = tanhf(a[2]);
      float og = 1.f / (1.f + expf(-a[3]));
      c_reg = fg * c_reg + ig * gg;
      hsh[u] = og * tanhf(c_reg);
    }
    __syncthreads();
    {
      float sk = 0.f, sw = 0.f, sv = 0.f;
      const float* rk = wk + u * 256;
      const float* rw = wwk + u * 256;
      const float* rv = wv + u * 256;
      for (int k = 0; k < 256; ++k) {
        float hv = hsh[k];
        sk = fmaf(rk[k], hv, sk);
        sw = fmaf(rw[k], hv, sw);
        sv = fmaf(rv[k], hv, sv);
      }
      kqr[u] = sk;
      kqw[u] = sw;
      vsh[u] = tanhf(sv);
    }
    __syncthreads();
    if (u < 20) {
      const float* Mr = &Msh[u * 257];
      float ss = 0.f, s1 = 0.f, s2 = 0.f;
      for (int k = 0; k < 256; ++k) {
        float m = Mr[k];
        ss = fmaf(m, m, ss);
        s1 = fmaf(kqr[k], m, s1);
        s2 = fmaf(kqw[k], m, s2);
      }
      float inv = 1.f / (sqrtf(ss) + EPSF);
      simr[u] = s1 * inv;
      simw[u] = s2 * inv;
    } else if (u == 20 || u == 21) {
      const float* q = (u == 20) ? kqr : kqw;
      float qq = 0.f;
      for (int k = 0; k < 256; ++k) qq = fmaf(q[k], q[k], qq);
      invq[u - 20] = 1.f / (sqrtf(qq) + EPSF);
    }
    __syncthreads();
    if (u < 2) {
      const float* sims = (u == 0) ? simr : simw;
      float inv = invq[u];
      unsigned mask = 0;
      float tv[4];
      int ti[4];
      for (int j = 0; j < 4; ++j) {
        float best = -3.4e38f;
        int bx = 0;
        for (int n = 0; n < 20; ++n)
          if (!((mask >> n) & 1u) && sims[n] > best) { best = sims[n]; bx = n; }
        mask |= 1u << bx;
        tv[j] = best * inv;
        ti[j] = bx;
      }
      float e1 = expf(tv[1] - tv[0]);
      float e2 = expf(tv[2] - tv[0]);
      float e3 = expf(tv[3] - tv[0]);
      float s = 1.f + e1 + e2 + e3;
      wsel[u][0] = 1.f / s; wsel[u][1] = e1 / s; wsel[u][2] = e2 / s; wsel[u][3] = e3 / s;
      isel[u][0] = ti[0]; isel[u][1] = ti[1]; isel[u][2] = ti[2]; isel[u][3] = ti[3];
    }
    __syncthreads();
    {
      float rvv = 0.f;
      for (int j = 0; j < 4; ++j)
        rvv = fmaf(wsel[0][j], Msh[isel[0][j] * 257 + u], rvv);
      float vv = vsh[u];
      for (int j = 0; j < 4; ++j)
        Msh[isel[1][j] * 257 + u] += wsel[1][j] * vv;
      inp[128 + u] = rvv;
    }
    __syncthreads();
  }
  if (u < 4) {
    float acc = wob[u];
    const float* wr = wo + u * 512;
    for (int k = 0; k < 256; ++k) acc = fmaf(wr[k], hsh[k], acc);
    for (int k = 0; k < 256; ++k) acc = fmaf(wr[256 + k], inp[128 + k], acc);
    ysh[u] = acc;
    out[b * 4 + u] = acc;
  }
  __syncthreads();
  if (u == 0) {
    float best = ysh[0];
    int bx = 0;
    for (int o = 1; o < 4; ++o)
      if (ysh[o] > best) { best = ysh[o]; bx = o; }
    out[1024 + b] = (float)bx;
  }
}

// ---------- launch ----------
extern "C" void kernel_launch(void* const* d_in, const int* in_sizes, int n_in,
                              void* d_out, int out_size, void* d_ws, size_t ws_size,
                              hipStream_t stream) {
  const float* x    = (const float*)d_in[0];
  const float* c1w  = (const float*)d_in[1];
  const float* c1b  = (const float*)d_in[2];
  const float* c2w  = (const float*)d_in[3];
  const float* c2b  = (const float*)d_in[4];
  const float* c3w  = (const float*)d_in[5];
  const float* c3b  = (const float*)d_in[6];
  const float* f1w  = (const float*)d_in[7];
  const float* f1b  = (const float*)d_in[8];
  const float* f2w  = (const float*)d_in[9];
  const float* f2b  = (const float*)d_in[10];
  const float* gam  = (const float*)d_in[11];
  const float* bet  = (const float*)d_in[12];
  const float* wi   = (const float*)d_in[13];
  const float* wh   = (const float*)d_in[14];
  const float* lb   = (const float*)d_in[15];
  const float* wk   = (const float*)d_in[16];
  const float* wwk  = (const float*)d_in[17];
  const float* wv   = (const float*)d_in[18];
  const float* wo   = (const float*)d_in[19];
  const float* wob  = (const float*)d_in[20];
  const float* mem0 = (const float*)d_in[21];
  float* out = (float*)d_out;

  if (ws_size >= (size_t)WS_BASE * sizeof(float)) {
    float* ws = (float*)d_ws;
    const bool full = ws_size >= (size_t)WS_FULL * sizeof(float);
    pack_kernel<<<3968, 256, 0, stream>>>(wi, wh, wk, wwk, wv, f1w, f2w, ws);
    enc_kernel<<<5120, 256, 0, stream>>>(x, c1w, c1b, c2w, c2b, c3w, c3b,
                                         f1b, f2b, ws);
    norm_kernel<<<128, 256, 0, stream>>>(ws, gam, bet);
    const float* gz = nullptr;
    if (full) {
      gz_kernel<<<320, 512, 0, stream>>>(ws, lb, ws + OFF_GZ);
      gz = ws + OFF_GZ;
    }
    scan_kernel<<<128, 1024, 0, stream>>>(ws, gz, lb, wo, wob, mem0, out);
  } else {
    fused_kernel<<<256, 256, 0, stream>>>(x, c1w, c1b, c2w, c2b, c3w, c3b,
                                          f1w, f1b, f2w, f2b, gam, bet,
                                          wi, wh, lb, wk, wwk, wv, wo, wob,
                                          mem0, out);
  }
}

// Round 11
// 1277.383 us; speedup vs baseline: 3.1231x; 1.0270x over previous
//
#include <hip/hip_runtime.h>
#include <hip/hip_bf16.h>

#define EPSF 1e-8f

// ---- workspace layout (floats) ----
#define OFF_WIT 0               // wiT4 [96 k4][1024 r] float4 = wi[r][4k4..+3]
#define N_WIT   393216
#define OFF_WHT 393216          // whT4 [64 k4][1024 r] float4
#define N_WHT   262144
#define OFF_PKT 655360          // pkT4 [64 k4][768 c] float4, c = m*256+o, m in {wk,wwk,wv}
#define N_PKT   196608
#define OFF_F1T 851968          // f1T4 [128 k4][256 o] float4
#define N_F1T   131072
#define OFF_F2T 983040          // f2T4 [64 k4][128 o] float4
#define N_F2T   32768
#define OFF_Z   1015808         // z [5120][128]
#define N_Z     655360
#define WS_BASE 1671168         // 6,684,672 bytes (tier-2)
#define OFF_GZ  1671168         // gz [5120 f][1024 r] = lb + wi[:, :128] @ z[f]
#define N_GZ    5242880
#define WS_FULL 6914048         // 27,656,192 bytes (tier-1)

// ---------- pack: transpose weights into ws (once per launch) ----------
__global__ __launch_bounds__(256) void pack_kernel(
    const float* __restrict__ wi, const float* __restrict__ wh,
    const float* __restrict__ wk, const float* __restrict__ wwk,
    const float* __restrict__ wv,
    const float* __restrict__ f1w, const float* __restrict__ f2w,
    float* __restrict__ ws) {
  int id = blockIdx.x * 256 + threadIdx.x;
  if (id < N_WIT) {  // ws[(k4*1024+r)*4+j] = wi[r*384 + k4*4 + j]
    int j = id & 3, r = (id >> 2) & 1023, k4 = id >> 12;
    ws[OFF_WIT + id] = wi[r * 384 + k4 * 4 + j];
    return;
  }
  id -= N_WIT;
  if (id < N_WHT) {  // ws[(k4*1024+r)*4+j] = wh[r*256 + k4*4 + j]
    int j = id & 3, r = (id >> 2) & 1023, k4 = id >> 12;
    ws[OFF_WHT + id] = wh[r * 256 + k4 * 4 + j];
    return;
  }
  id -= N_WHT;
  if (id < N_PKT) {  // ws[(k4*768+c)*4+j] = {wk,wwk,wv}[m][o*256 + k4*4 + j]
    int j = id & 3;
    int q = id >> 2;
    int c = q % 768, k4 = q / 768;
    int m = c >> 8, o = c & 255;
    int col = o * 256 + k4 * 4 + j;
    float v = (m == 0) ? wk[col] : (m == 1) ? wwk[col] : wv[col];
    ws[OFF_PKT + id] = v;
    return;
  }
  id -= N_PKT;
  if (id < N_F1T) {  // ws[(k4*256+o)*4+m] = f1w[o*512+4k4+m]
    int m = id & 3, o = (id >> 2) & 255, k4 = id >> 10;
    ws[OFF_F1T + id] = f1w[o * 512 + k4 * 4 + m];
    return;
  }
  id -= N_F1T;
  if (id < N_F2T) {  // ws[(k4*128+o)*4+m] = f2w[o*256+4k4+m]
    int m = id & 3, o = (id >> 2) & 127, k4 = id >> 9;
    ws[OFF_F2T + id] = f2w[o * 256 + k4 * 4 + m];
  }
}

// ---------- encoder: one block per frame; register patches + uniform weights ----------
__global__ __launch_bounds__(256) void enc_kernel(
    const float* __restrict__ x,
    const float* __restrict__ w1, const float* __restrict__ b1,
    const float* __restrict__ w2, const float* __restrict__ b2,
    const float* __restrict__ w3, const float* __restrict__ b3,
    const float* __restrict__ f1b, const float* __restrict__ f2b,
    float* __restrict__ ws) {
  __shared__ __align__(16) float xs[1024];        // 32x32
  __shared__ __align__(16) float c1s[512 * 19];   // 32ch x 16 rows, pad 19
  __shared__ __align__(16) float c2s[256 * 9];    // 32ch x 8 rows, pad 9
  __shared__ __align__(16) float c3s[512];        // 32 x 4 x 4 (NCHW flatten)
  __shared__ __align__(16) float h1s[256];

  const float4* __restrict__ f1T4 = (const float4*)(ws + OFF_F1T);
  const float4* __restrict__ f2T4 = (const float4*)(ws + OFF_F2T);
  float* __restrict__ z = ws + OFF_Z;

  const int f = blockIdx.x;  // = b*20 + t
  const int tid = threadIdx.x;

  for (int i = tid; i < 1024; i += 256) xs[i] = x[f * 1024 + i];
  __syncthreads();

  // conv1: thread = pixel (16x16); patch in regs; 32 ocs with uniform weights
  {
    int oy = tid >> 4, ox = tid & 15;
    float patch[16];
    #pragma unroll
    for (int ky = 0; ky < 4; ++ky) {
      int iy = oy * 2 - 1 + ky;
      #pragma unroll
      for (int kx = 0; kx < 4; ++kx) {
        int ix = ox * 2 - 1 + kx;
        patch[ky * 4 + kx] =
            ((unsigned)iy <= 31u && (unsigned)ix <= 31u) ? xs[iy * 32 + ix] : 0.f;
      }
    }
    for (int oc = 0; oc < 32; ++oc) {
      float acc = b1[oc];
      #pragma unroll
      for (int k = 0; k < 16; ++k) acc = fmaf(patch[k], w1[oc * 16 + k], acc);
      c1s[(oc * 16 + oy) * 19 + ox] = fmaxf(acc, 0.f);
    }
  }
  __syncthreads();

  // conv2: wave og handles ocs og*8..+7; lane = pixel of 8x8; patch regs per ic
  {
    int pix = tid & 63;
    int og = __builtin_amdgcn_readfirstlane(tid >> 6);
    int oy = pix >> 3, ox = pix & 7;
    float acc[8];
    #pragma unroll
    for (int j = 0; j < 8; ++j) acc[j] = b2[og * 8 + j];
    for (int ic = 0; ic < 32; ++ic) {
      float patch[16];
      #pragma unroll
      for (int ky = 0; ky < 4; ++ky) {
        int iy = oy * 2 - 1 + ky;
        #pragma unroll
        for (int kx = 0; kx < 4; ++kx) {
          int ix = ox * 2 - 1 + kx;
          patch[ky * 4 + kx] = ((unsigned)iy <= 15u && (unsigned)ix <= 15u)
                                   ? c1s[(ic * 16 + iy) * 19 + ix] : 0.f;
        }
      }
      #pragma unroll
      for (int j = 0; j < 8; ++j) {
        const float* wr = w2 + ((og * 8 + j) * 32 + ic) * 16;  // wave-uniform
        #pragma unroll
        for (int k = 0; k < 16; ++k) acc[j] = fmaf(patch[k], wr[k], acc[j]);
      }
    }
    #pragma unroll
    for (int j = 0; j < 8; ++j)
      c2s[((og * 8 + j) * 8 + oy) * 9 + ox] = fmaxf(acc[j], 0.f);
  }
  __syncthreads();

  // conv3: thread = (pixel of 4x4, grp of 2 ocs); patch regs per ic
  {
    int pix = tid & 15, grp = tid >> 4;
    int oy = pix >> 2, ox = pix & 3;
    float a0 = b3[grp * 2], a1 = b3[grp * 2 + 1];
    for (int ic = 0; ic < 32; ++ic) {
      float patch[16];
      #pragma unroll
      for (int ky = 0; ky < 4; ++ky) {
        int iy = oy * 2 - 1 + ky;
        #pragma unroll
        for (int kx = 0; kx < 4; ++kx) {
          int ix = ox * 2 - 1 + kx;
          patch[ky * 4 + kx] = ((unsigned)iy <= 7u && (unsigned)ix <= 7u)
                                   ? c2s[(ic * 8 + iy) * 9 + ix] : 0.f;
        }
      }
      const float4* wa = (const float4*)(w3 + ((grp * 2 + 0) * 32 + ic) * 16);
      const float4* wb = (const float4*)(w3 + ((grp * 2 + 1) * 32 + ic) * 16);
      #pragma unroll
      for (int q = 0; q < 4; ++q) {
        float4 qa = wa[q], qb = wb[q];
        a0 = fmaf(patch[q * 4 + 0], qa.x, a0);
        a0 = fmaf(patch[q * 4 + 1], qa.y, a0);
        a0 = fmaf(patch[q * 4 + 2], qa.z, a0);
        a0 = fmaf(patch[q * 4 + 3], qa.w, a0);
        a1 = fmaf(patch[q * 4 + 0], qb.x, a1);
        a1 = fmaf(patch[q * 4 + 1], qb.y, a1);
        a1 = fmaf(patch[q * 4 + 2], qb.z, a1);
        a1 = fmaf(patch[q * 4 + 3], qb.w, a1);
      }
    }
    c3s[(grp * 2 + 0) * 16 + pix] = fmaxf(a0, 0.f);
    c3s[(grp * 2 + 1) * 16 + pix] = fmaxf(a1, 0.f);
  }
  __syncthreads();

  // fc1: 512 -> 256, relu; coalesced float4 weights
  {
    float acc = f1b[tid];
    #pragma unroll 8
    for (int k4 = 0; k4 < 128; ++k4) {
      float4 cv = ((const float4*)c3s)[k4];
      float4 w = f1T4[k4 * 256 + tid];
      acc = fmaf(w.x, cv.x, acc);
      acc = fmaf(w.y, cv.y, acc);
      acc = fmaf(w.z, cv.z, acc);
      acc = fmaf(w.w, cv.w, acc);
    }
    h1s[tid] = fmaxf(acc, 0.f);
  }
  __syncthreads();

  // fc2: 256 -> 128, relu -> z
  if (tid < 128) {
    float acc = f2b[tid];
    #pragma unroll 8
    for (int k4 = 0; k4 < 64; ++k4) {
      float4 hv = ((const float4*)h1s)[k4];
      float4 w = f2T4[k4 * 128 + tid];
      acc = fmaf(w.x, hv.x, acc);
      acc = fmaf(w.y, hv.y, acc);
      acc = fmaf(w.z, hv.z, acc);
      acc = fmaf(w.w, hv.w, acc);
    }
    z[f * 128 + tid] = fmaxf(acc, 0.f);
  }
}

// ---------- context norm over time ----------
__global__ __launch_bounds__(256) void norm_kernel(
    float* __restrict__ ws,
    const float* __restrict__ gamma, const float* __restrict__ beta) {
  float* z = ws + OFF_Z;
  int g = blockIdx.x * 256 + threadIdx.x;  // B*D = 32768
  int b = g >> 7, d = g & 127;
  float vals[20];
  float mu = 0.f;
  #pragma unroll
  for (int t = 0; t < 20; ++t) {
    float v = z[(b * 20 + t) * 128 + d];
    vals[t] = v;
    mu += v;
  }
  mu *= (1.f / 20.f);
  float var = 0.f;
  #pragma unroll
  for (int t = 0; t < 20; ++t) {
    float dd = vals[t] - mu;
    var = fmaf(dd, dd, var);
  }
  var *= (1.f / 19.f);
  float inv = 1.f / sqrtf(var + EPSF);
  float ga = gamma[d], be = beta[d];
  #pragma unroll
  for (int t = 0; t < 20; ++t)
    z[(b * 20 + t) * 128 + d] = fmaf((vals[t] - mu) * inv, ga, be);
}

// ---------- gz: gates_z[f][r] = lb[r] + wi[r, :128] @ z[f]  (recurrence-free) ----------
__global__ __launch_bounds__(512) void gz_kernel(
    const float* __restrict__ ws, const float* __restrict__ lb,
    float* __restrict__ gz) {
  __shared__ __align__(16) float zs[16][128];
  const float4* wiT4 = (const float4*)(ws + OFF_WIT);  // [96 k4][1024 r]
  const float* zz = ws + OFF_Z;
  const int tid = threadIdx.x;
  const int f0 = blockIdx.x * 16;

  for (int i = tid; i < 2048; i += 512) zs[i >> 7][i & 127] = zz[f0 * 128 + i];
  __syncthreads();

  float acc0[16], acc1[16];
  const float b0v = lb[tid], b1v = lb[tid + 512];
  #pragma unroll
  for (int f = 0; f < 16; ++f) { acc0[f] = b0v; acc1[f] = b1v; }

  for (int k4 = 0; k4 < 32; ++k4) {  // k < 128: the z part of wi
    float4 w0 = wiT4[k4 * 1024 + tid];
    float4 w1 = wiT4[k4 * 1024 + tid + 512];
    #pragma unroll
    for (int f = 0; f < 16; ++f) {
      float4 zv = *(const float4*)&zs[f][k4 * 4];  // uniform addr -> broadcast
      acc0[f] = fmaf(w0.x, zv.x, acc0[f]);
      acc0[f] = fmaf(w0.y, zv.y, acc0[f]);
      acc0[f] = fmaf(w0.z, zv.z, acc0[f]);
      acc0[f] = fmaf(w0.w, zv.w, acc0[f]);
      acc1[f] = fmaf(w1.x, zv.x, acc1[f]);
      acc1[f] = fmaf(w1.y, zv.y, acc1[f]);
      acc1[f] = fmaf(w1.z, zv.z, acc1[f]);
      acc1[f] = fmaf(w1.w, zv.w, acc1[f]);
    }
  }
  #pragma unroll
  for (int f = 0; f < 16; ++f) {
    gz[(f0 + f) * 1024 + tid] = acc0[f];
    gz[(f0 + f) * 1024 + 512 + tid] = acc1[f];
  }
}

// ---------- scan: 1024 threads, 2 batch/block; gz + per-block k4 rotation ----------
// Rotation decorrelates the L2 address sweep of the 16 co-XCD blocks (bank
// hotspot theory). Changes only fp32 accumulation ORDER (same term set).
__global__ __launch_bounds__(1024, 2) void scan_kernel(
    const float* __restrict__ ws, const float* __restrict__ gz,
    const float* __restrict__ lb, const float* __restrict__ wo,
    const float* __restrict__ wob, const float* __restrict__ mem_init,
    float* __restrict__ out) {
  __shared__ float Msh[2][20 * 257];
  __shared__ __align__(16) float gsh[2][1024];
  __shared__ __align__(16) float inp[2][384];   // [z(128) | r(256)]
  __shared__ __align__(16) float hsh[2][256];
  __shared__ float kqsh[2][2][256];             // [bl][head][k]
  __shared__ float vsh[2][256];
  __shared__ float sims[2][2][20];
  __shared__ float invq[2][2];
  __shared__ float wsel[2][2][4];
  __shared__ int isel[2][2][4];
  __shared__ float ysh[2][4];

  const int r = threadIdx.x;  // 0..1023
  const int b0 = blockIdx.x * 2;
  // blockIdx -> XCD is round-robin mod 8; (blockIdx>>3) enumerates co-XCD blocks.
  const int rot = ((blockIdx.x >> 3) & 15) << 2;  // 0,4,...,60
  const float4* wiT4 = (const float4*)(ws + OFF_WIT);  // [96 k4][1024 r]
  const float4* whT4 = (const float4*)(ws + OFF_WHT);  // [64 k4][1024 r]
  const float4* pkT4 = (const float4*)(ws + OFF_PKT);  // [64 k4][768 c]
  const float* zz = ws + OFF_Z;
  const int k4s = gz ? 32 : 0;      // with gz, wi's z-columns are prefolded
  const int wiRange = 96 - k4s;     // 64 (gz) or 96

  #pragma unroll
  for (int bl = 0; bl < 2; ++bl)
    for (int idx = r; idx < 5120; idx += 1024)
      Msh[bl][(idx >> 8) * 257 + (idx & 255)] = mem_init[idx];
  if (r < 512) {
    int bl = r >> 8, u = r & 255;
    hsh[bl][u] = 0.f;
    inp[bl][128 + u] = 0.f;
  }
  float c_reg = 0.f;
  const float bias = lb[r];
  __syncthreads();

  for (int t = 0; t < 20; ++t) {
    if (!gz && r < 256) {
      int bl = r >> 7, d = r & 127;
      inp[bl][d] = zz[((b0 + bl) * 20 + t) * 128 + d];
    }
    __syncthreads();

    // gates: thread r = row r; both batch elements from one weight load
    float a0, a1;
    if (gz) {
      a0 = gz[(b0 * 20 + t) * 1024 + r];
      a1 = gz[((b0 + 1) * 20 + t) * 1024 + r];
    } else {
      a0 = bias;
      a1 = bias;
    }
    {
      const float4* ip0 = (const float4*)inp[0];
      const float4* ip1 = (const float4*)inp[1];
      #pragma unroll 8
      for (int j = 0; j < 64; ++j) {  // gz path: wiRange==64
        int kk = j + rot;
        if (kk >= 64) kk -= 64;
        int k4 = k4s + kk;
        if (k4s == 0 && j == 0) { /* placeholder keeps structure identical */ }
        float4 w = wiT4[k4 * 1024 + r];
        float4 z0 = ip0[k4], z1 = ip1[k4];
        a0 = fmaf(w.x, z0.x, a0); a1 = fmaf(w.x, z1.x, a1);
        a0 = fmaf(w.y, z0.y, a0); a1 = fmaf(w.y, z1.y, a1);
        a0 = fmaf(w.z, z0.z, a0); a1 = fmaf(w.z, z1.z, a1);
        a0 = fmaf(w.w, z0.w, a0); a1 = fmaf(w.w, z1.w, a1);
      }
      // non-gz fallback: cover the remaining k4 (0..31) unrotated
      if (!gz) {
        #pragma unroll 8
        for (int k4 = 0; k4 < 32; ++k4) {
          float4 w = wiT4[k4 * 1024 + r];
          float4 z0 = ip0[k4], z1 = ip1[k4];
          a0 = fmaf(w.x, z0.x, a0); a1 = fmaf(w.x, z1.x, a1);
          a0 = fmaf(w.y, z0.y, a0); a1 = fmaf(w.y, z1.y, a1);
          a0 = fmaf(w.z, z0.z, a0); a1 = fmaf(w.z, z1.z, a1);
          a0 = fmaf(w.w, z0.w, a0); a1 = fmaf(w.w, z1.w, a1);
        }
      }
      const float4* hp0 = (const float4*)hsh[0];
      const float4* hp1 = (const float4*)hsh[1];
      #pragma unroll 8
      for (int j = 0; j < 64; ++j) {
        int k4 = j + rot;
        if (k4 >= 64) k4 -= 64;
        float4 w = whT4[k4 * 1024 + r];
        float4 h0 = hp0[k4], h1 = hp1[k4];
        a0 = fmaf(w.x, h0.x, a0); a1 = fmaf(w.x, h1.x, a1);
        a0 = fmaf(w.y, h0.y, a0); a1 = fmaf(w.y, h1.y, a1);
        a0 = fmaf(w.z, h0.z, a0); a1 = fmaf(w.z, h1.z, a1);
        a0 = fmaf(w.w, h0.w, a0); a1 = fmaf(w.w, h1.w, a1);
      }
    }
    gsh[0][r] = a0;
    gsh[1][r] = a1;
    __syncthreads();

    // LSTM cell (torch order i,f,g,o); thread r<512 owns (bl, unit)
    if (r < 512) {
      int bl = r >> 8, u = r & 255;
      float ig = gsh[bl][u], fg = gsh[bl][256 + u];
      float gg = gsh[bl][512 + u], og = gsh[bl][768 + u];
      c_reg = (1.f / (1.f + expf(-fg))) * c_reg +
              (1.f / (1.f + expf(-ig))) * tanhf(gg);
      hsh[bl][u] = (1.f / (1.f + expf(-og))) * tanhf(c_reg);
    }
    __syncthreads();

    // head projections: thread r<768 owns one row of {wk,wwk,wv}, both bl
    if (r < 768) {
      int m = r >> 8, o = r & 255;
      float s0 = 0.f, s1 = 0.f;
      const float4* hp0 = (const float4*)hsh[0];
      const float4* hp1 = (const float4*)hsh[1];
      #pragma unroll 8
      for (int j = 0; j < 64; ++j) {
        int k4 = j + rot;
        if (k4 >= 64) k4 -= 64;
        float4 w = pkT4[k4 * 768 + r];
        float4 h0 = hp0[k4], h1 = hp1[k4];
        s0 = fmaf(w.x, h0.x, s0); s1 = fmaf(w.x, h1.x, s1);
        s0 = fmaf(w.y, h0.y, s0); s1 = fmaf(w.y, h1.y, s1);
        s0 = fmaf(w.z, h0.z, s0); s1 = fmaf(w.z, h1.z, s1);
        s0 = fmaf(w.w, h0.w, s0); s1 = fmaf(w.w, h1.w, s1);
      }
      if (m < 2) {
        kqsh[0][m][o] = s0;
        kqsh[1][m][o] = s1;
      } else {
        vsh[0][o] = tanhf(s0);
        vsh[1][o] = tanhf(s1);
      }
    }
    __syncthreads();

    // per-slot norms + sims (8 lanes/slot, shfl); query norms on r=320..323
    if (r < 320) {
      int bl = r >= 160;
      int q = bl ? r - 160 : r;
      int n = q >> 3, l = q & 7;
      const float* Mr = &Msh[bl][n * 257];
      float ss = 0.f, s1 = 0.f, s2 = 0.f;
      for (int i = 0; i < 32; ++i) {
        int k = l + 8 * i;
        float m = Mr[k];
        ss = fmaf(m, m, ss);
        s1 = fmaf(kqsh[bl][0][k], m, s1);
        s2 = fmaf(kqsh[bl][1][k], m, s2);
      }
      ss += __shfl_xor(ss, 1); s1 += __shfl_xor(s1, 1); s2 += __shfl_xor(s2, 1);
      ss += __shfl_xor(ss, 2); s1 += __shfl_xor(s1, 2); s2 += __shfl_xor(s2, 2);
      ss += __shfl_xor(ss, 4); s1 += __shfl_xor(s1, 4); s2 += __shfl_xor(s2, 4);
      if (l == 0) {
        float inv = 1.f / (sqrtf(ss) + EPSF);
        sims[bl][0][n] = s1 * inv;
        sims[bl][1][n] = s2 * inv;
      }
    } else if (r < 324) {
      int bl2 = (r - 320) >> 1, hd = r & 1;
      float qq = 0.f;
      for (int k = 0; k < 256; ++k) {
        float q = kqsh[bl2][hd][k];
        qq = fmaf(q, q, qq);
      }
      invq[bl2][hd] = 1.f / (sqrtf(qq) + EPSF);
    }
    __syncthreads();

    // top-4 (strict >, lowest index on tie) + softmax; 4 threads: (bl, head)
    if (r < 4) {
      int bl = r >> 1, hd = r & 1;
      const float* sm = sims[bl][hd];
      float inv = invq[bl][hd];
      unsigned mask = 0;
      float tv[4];
      int ti[4];
      for (int j = 0; j < 4; ++j) {
        float best = -3.4e38f;
        int bx = 0;
        for (int n = 0; n < 20; ++n)
          if (!((mask >> n) & 1u) && sm[n] > best) { best = sm[n]; bx = n; }
        mask |= 1u << bx;
        tv[j] = best * inv;
        ti[j] = bx;
      }
      float e0 = 1.f;
      float e1 = expf(tv[1] - tv[0]);
      float e2 = expf(tv[2] - tv[0]);
      float e3 = expf(tv[3] - tv[0]);
      float s = e0 + e1 + e2 + e3;
      wsel[bl][hd][0] = e0 / s; wsel[bl][hd][1] = e1 / s;
      wsel[bl][hd][2] = e2 / s; wsel[bl][hd][3] = e3 / s;
      isel[bl][hd][0] = ti[0]; isel[bl][hd][1] = ti[1];
      isel[bl][hd][2] = ti[2]; isel[bl][hd][3] = ti[3];
    }
    __syncthreads();

    // read gather (old M) then weighted scatter-add; (bl,u) column exclusive
    if (r < 512) {
      int bl = r >> 8, u = r & 255;
      float rvv = 0.f;
      #pragma unroll
      for (int j = 0; j < 4; ++j)
        rvv = fmaf(wsel[bl][0][j], Msh[bl][isel[bl][0][j] * 257 + u], rvv);
      float vv = vsh[bl][u];
      #pragma unroll
      for (int j = 0; j < 4; ++j)
        Msh[bl][isel[bl][1][j] * 257 + u] += wsel[bl][1][j] * vv;
      inp[bl][128 + u] = rvv;
    }
    __syncthreads();
  }

  // epilogue: y = [h, r] @ wo.T + wo_b; argmax (first max wins)
  if (r < 8) {
    int bl = r >> 2, o = r & 3;
    float acc = wob[o];
    const float* wr = wo + o * 512;
    for (int k = 0; k < 256; ++k) acc = fmaf(wr[k], hsh[bl][k], acc);
    for (int k = 0; k < 256; ++k) acc = fmaf(wr[256 + k], inp[bl][128 + k], acc);
    ysh[bl][o] = acc;
    out[(b0 + bl) * 4 + o] = acc;
  }
  __syncthreads();
  if (r < 2) {
    float best = ysh[r][0];
    int bx = 0;
    #pragma unroll
    for (int o = 1; o < 4; ++o)
      if (ysh[r][o] > best) { best = ysh[r][o]; bx = o; }
    out[1024 + b0 + r] = (float)bx;
  }
}

// ---------- fallback: proven round-4 single fused kernel (no workspace) ----------
__global__ __launch_bounds__(256) void fused_kernel(
    const float* __restrict__ x,
    const float* __restrict__ w1, const float* __restrict__ b1,
    const float* __restrict__ w2, const float* __restrict__ b2,
    const float* __restrict__ w3, const float* __restrict__ b3,
    const float* __restrict__ f1w, const float* __restrict__ f1b,
    const float* __restrict__ f2w, const float* __restrict__ f2b,
    const float* __restrict__ gamma, const float* __restrict__ beta,
    const float* __restrict__ wi, const float* __restrict__ wh,
    const float* __restrict__ lb, const float* __restrict__ wk,
    const float* __restrict__ wwk, const float* __restrict__ wv,
    const float* __restrict__ wo, const float* __restrict__ wob,
    const float* __restrict__ mem_init, float* __restrict__ out) {
  __shared__ float smem[15104];
  __shared__ float simr[20], simw[20], invq[2], wsel[2][4], ysh[4];
  __shared__ int isel[2][4];
  float* z_all = smem;
  float* pool = smem + 2560;
  float* xs = pool;
  float* c1s = pool + 1024;
  float* c2s = pool + 9216;
  float* c3s = pool + 11264;
  float* h1s = pool + 11776;
  float* w1s = pool + 12032;
  float* Msh = pool;
  float* inp = pool + 5140;
  float* hsh = pool + 5524;
  float* kqr = pool + 5780;
  float* kqw = pool + 6036;
  float* vsh = pool + 6292;
  const int tid = threadIdx.x;
  const int b = blockIdx.x;
  for (int i = tid; i < 512; i += 256) w1s[i] = w1[i];
  for (int f = 0; f < 20; ++f) {
    for (int i = tid; i < 1024; i += 256) xs[i] = x[(b * 20 + f) * 1024 + i];
    __syncthreads();
    for (int i = 0; i < 32; ++i) {
      int idx = i * 256 + tid;
      int oc = idx >> 8, pix = idx & 255, oy = pix >> 4, ox = pix & 15;
      float acc = b1[oc];
      for (int ky = 0; ky < 4; ++ky) {
        int iy = oy * 2 - 1 + ky;
        if ((unsigned)iy > 31u) continue;
        for (int kx = 0; kx < 4; ++kx) {
          int ix = ox * 2 - 1 + kx;
          if ((unsigned)ix > 31u) continue;
          acc = fmaf(xs[iy * 32 + ix], w1s[oc * 16 + ky * 4 + kx], acc);
        }
      }
      c1s[idx] = fmaxf(acc, 0.f);
    }
    __syncthreads();
    {
      int oc = tid >> 3, pg = tid & 7;
      float acc[8];
      float bb = b2[oc];
      for (int i = 0; i < 8; ++i) acc[i] = bb;
      for (int ic = 0; ic < 32; ++ic) {
        const float* in = &c1s[ic * 256];
        const float* wv_ = &w2[(oc * 32 + ic) * 16];
        for (int i = 0; i < 8; ++i) {
          int p = pg + 8 * i;
          int oy = p >> 3, ox = p & 7;
          for (int ky = 0; ky < 4; ++ky) {
            int iy = oy * 2 - 1 + ky;
            if ((unsigned)iy > 15u) continue;
            for (int kx = 0; kx < 4; ++kx) {
              int ix = ox * 2 - 1 + kx;
              if ((unsigned)ix > 15u) continue;
              acc[i] = fmaf(in[iy * 16 + ix], wv_[ky * 4 + kx], acc[i]);
            }
          }
        }
      }
      for (int i = 0; i < 8; ++i) c2s[oc * 64 + pg + 8 * i] = fmaxf(acc[i], 0.f);
    }
    __syncthreads();
    {
      int oc = tid >> 3, pg = tid & 7;
      float bb = b3[oc];
      float acc0 = bb, acc1 = bb;
      int p0 = pg, p1 = pg + 8;
      int oy0 = p0 >> 2, ox0 = p0 & 3, oy1 = p1 >> 2, ox1 = p1 & 3;
      for (int ic = 0; ic < 32; ++ic) {
        const float* in = &c2s[ic * 64];
        const float* wv_ = &w3[(oc * 32 + ic) * 16];
        for (int ky = 0; ky < 4; ++ky) {
          int iy0 = oy0 * 2 - 1 + ky, iy1 = oy1 * 2 - 1 + ky;
          for (int kx = 0; kx < 4; ++kx) {
            float w = wv_[ky * 4 + kx];
            int ix0 = ox0 * 2 - 1 + kx, ix1 = ox1 * 2 - 1 + kx;
            if ((unsigned)iy0 <= 7u && (unsigned)ix0 <= 7u)
              acc0 = fmaf(in[iy0 * 8 + ix0], w, acc0);
            if ((unsigned)iy1 <= 7u && (unsigned)ix1 <= 7u)
              acc1 = fmaf(in[iy1 * 8 + ix1], w, acc1);
          }
        }
      }
      c3s[oc * 16 + p0] = fmaxf(acc0, 0.f);
      c3s[oc * 16 + p1] = fmaxf(acc1, 0.f);
    }
    __syncthreads();
    {
      float acc = f1b[tid];
      const float* wr = f1w + tid * 512;
      for (int k = 0; k < 512; ++k) acc = fmaf(wr[k], c3s[k], acc);
      h1s[tid] = fmaxf(acc, 0.f);
    }
    __syncthreads();
    if (tid < 128) {
      float acc = f2b[tid];
      const float* wr = f2w + tid * 256;
      for (int k = 0; k < 256; ++k) acc = fmaf(wr[k], h1s[k], acc);
      z_all[f * 128 + tid] = fmaxf(acc, 0.f);
    }
    __syncthreads();
  }
  if (tid < 128) {
    float mu = 0.f;
    for (int t = 0; t < 20; ++t) mu += z_all[t * 128 + tid];
    mu *= (1.f / 20.f);
    float var = 0.f;
    for (int t = 0; t < 20; ++t) {
      float dd = z_all[t * 128 + tid] - mu;
      var = fmaf(dd, dd, var);
    }
    var *= (1.f / 19.f);
    float inv = 1.f / sqrtf(var + EPSF);
    float ga = gamma[tid], be = beta[tid];
    for (int t = 0; t < 20; ++t)
      z_all[t * 128 + tid] = fmaf((z_all[t * 128 + tid] - mu) * inv, ga, be);
  }
  for (int idx = tid; idx < 20 * 256; idx += 256)
    Msh[(idx >> 8) * 257 + (idx & 255)] = mem_init[idx];
  hsh[tid] = 0.f;
  inp[128 + tid] = 0.f;
  float c_reg = 0.f;
  __syncthreads();
  const int u = tid;
  for (int t = 0; t < 20; ++t) {
    if (u < 128) inp[u] = z_all[t * 128 + u];
    __syncthreads();
    float a[4];
    for (int g = 0; g < 4; ++g) {
      int row = g * 256 + u;
      float acc = lb[row];
      const float* wr = wi + row * 384;
      for (int k = 0; k < 384; ++k) acc = fmaf(wr[k], inp[k], acc);
      const float* hr = wh + row * 256;
      for (int k = 0; k < 256; ++k) acc = fmaf(hr[k], hsh[k], acc);
      a[g] = acc;
    }
    __syncthreads();
    {
      float ig = 1.f / (1.f + expf(-a[0]));
      float fg = 1.f / (1.f + expf(-a[1]));
      float gg = tanhf(a[2]);
      float og = 1.f / (1.f + expf(-a[3]));
      c_reg = fg * c_reg + ig * gg;
      hsh[u] = og * tanhf(c_reg);
    }
    __syncthreads();
    {
      float sk = 0.f, sw = 0.f, sv = 0.f;
      const float* rk = wk + u * 256;
      const float* rw = wwk + u * 256;
      const float* rv = wv + u * 256;
      for (int k = 0; k < 256; ++k) {
        float hv = hsh[k];
        sk = fmaf(rk[k], hv, sk);
        sw = fmaf(rw[k], hv, sw);
        sv = fmaf(rv[k], hv, sv);
      }
      kqr[u] = sk;
      kqw[u] = sw;
      vsh[u] = tanhf(sv);
    }
    __syncthreads();
    if (u < 20) {
      const float* Mr = &Msh[u * 257];
      float ss = 0.f, s1 = 0.f, s2 = 0.f;
      for (int k = 0; k < 256; ++k) {
        float m = Mr[k];
        ss = fmaf(m, m, ss);
        s1 = fmaf(kqr[k], m, s1);
        s2 = fmaf(kqw[k], m, s2);
      }
      float inv = 1.f / (sqrtf(ss) + EPSF);
      simr[u] = s1 * inv;
      simw[u] = s2 * inv;
    } else if (u == 20 || u == 21) {
      const float* q = (u == 20) ? kqr : kqw;
      float qq = 0.f;
      for (int k = 0; k < 256; ++k) qq = fmaf(q[k], q[k], qq);
      invq[u - 20] = 1.f / (sqrtf(qq) + EPSF);
    }
    __syncthreads();
    if (u < 2) {
      const float* sims = (u == 0) ? simr : simw;
      float inv = invq[u];
      unsigned mask = 0;
      float tv[4];
      int ti[4];
      for (int j = 0; j < 4; ++j) {
        float best = -3.4e38f;
        int bx = 0;
        for (int n = 0; n < 20; ++n)
          if (!((mask >> n) & 1u) && sims[n] > best) { best = sims[n]; bx = n; }
        mask |= 1u << bx;
        tv[j] = best * inv;
        ti[j] = bx;
      }
      float e1 = expf(tv[1] - tv[0]);
      float e2 = expf(tv[2] - tv[0]);
      float e3 = expf(tv[3] - tv[0]);
      float s = 1.f + e1 + e2 + e3;
      wsel[u][0] = 1.f / s; wsel[u][1] = e1 / s; wsel[u][2] = e2 / s; wsel[u][3] = e3 / s;
      isel[u][0] = ti[0]; isel[u][1] = ti[1]; isel[u][2] = ti[2]; isel[u][3] = ti[3];
    }
    __syncthreads();
    {
      float rvv = 0.f;
      for (int j = 0; j < 4; ++j)
        rvv = fmaf(wsel[0][j], Msh[isel[0][j] * 257 + u], rvv);
      float vv = vsh[u];
      for (int j = 0; j < 4; ++j)
        Msh[isel[1][j] * 257 + u] += wsel[1][j] * vv;
      inp[128 + u] = rvv;
    }
    __syncthreads();
  }
  if (u < 4) {
    float acc = wob[u];
    const float* wr = wo + u * 512;
    for (int k = 0; k < 256; ++k) acc = fmaf(wr[k], hsh[k], acc);
    for (int k = 0; k < 256; ++k) acc = fmaf(wr[256 + k], inp[128 + k], acc);
    ysh[u] = acc;
    out[b * 4 + u] = acc;
  }
  __syncthreads();
  if (u == 0) {
    float best = ysh[0];
    int bx = 0;
    for (int o = 1; o < 4; ++o)
      if (ysh[o] > best) { best = ysh[o]; bx = o; }
    out[1024 + b] = (float)bx;
  }
}

// ---------- launch ----------
extern "C" void kernel_launch(void* const* d_in, const int* in_sizes, int n_in,
                              void* d_out, int out_size, void* d_ws, size_t ws_size,
                              hipStream_t stream) {
  const float* x    = (const float*)d_in[0];
  const float* c1w  = (const float*)d_in[1];
  const float* c1b  = (const float*)d_in[2];
  const float* c2w  = (const float*)d_in[3];
  const float* c2b  = (const float*)d_in[4];
  const float* c3w  = (const float*)d_in[5];
  const float* c3b  = (const float*)d_in[6];
  const float* f1w  = (const float*)d_in[7];
  const float* f1b  = (const float*)d_in[8];
  const float* f2w  = (const float*)d_in[9];
  const float* f2b  = (const float*)d_in[10];
  const float* gam  = (const float*)d_in[11];
  const float* bet  = (const float*)d_in[12];
  const float* wi   = (const float*)d_in[13];
  const float* wh   = (const float*)d_in[14];
  const float* lb   = (const float*)d_in[15];
  const float* wk   = (const float*)d_in[16];
  const float* wwk  = (const float*)d_in[17];
  const float* wv   = (const float*)d_in[18];
  const float* wo   = (const float*)d_in[19];
  const float* wob  = (const float*)d_in[20];
  const float* mem0 = (const float*)d_in[21];
  float* out = (float*)d_out;

  if (ws_size >= (size_t)WS_BASE * sizeof(float)) {
    float* ws = (float*)d_ws;
    const bool full = ws_size >= (size_t)WS_FULL * sizeof(float);
    pack_kernel<<<3968, 256, 0, stream>>>(wi, wh, wk, wwk, wv, f1w, f2w, ws);
    enc_kernel<<<5120, 256, 0, stream>>>(x, c1w, c1b, c2w, c2b, c3w, c3b,
                                         f1b, f2b, ws);
    norm_kernel<<<128, 256, 0, stream>>>(ws, gam, bet);
    const float* gz = nullptr;
    if (full) {
      gz_kernel<<<320, 512, 0, stream>>>(ws, lb, ws + OFF_GZ);
      gz = ws + OFF_GZ;
    }
    scan_kernel<<<128, 1024, 0, stream>>>(ws, gz, lb, wo, wob, mem0, out);
  } else {
    fused_kernel<<<256, 256, 0, stream>>>(x, c1w, c1b, c2w, c2b, c3w, c3b,
                                          f1w, f1b, f2w, f2b, gam, bet,
                                          wi, wh, lb, wk, wwk, wv, wo, wob,
                                          mem0, out);
  }
}